// Round 1
// baseline (3187.503 us; speedup 1.0000x reference)
//
#include <hip/hip_runtime.h>
#include <math.h>

#define EPSB 1e-5f

// Bi=128 Bc=64 T=32 C=300 OQK=75 H=128 LAT=1024
// stacked padded o-dim (464): q rows [0,80) (75 real), k [80,160) (75 real), v [160,464) (300 real)
// ws layout (float offsets):
static const long OFS_BASE  = 0;                      // 128*128
static const long OFS_BALL  = 16384;                  // 128*464
static const long OFS_MEAN  = 75776;                  // 128*1024
static const long OFS_KALLT = 206848;                 // 128*300*464 = 17,817,600
static const long OFS_RAW   = 206848 + 17817600;      // 128*464*300 (dead after k_bnt)
static const long OFS_X     = OFS_RAW;                // alias: 128*64*300
static const long OFS_H1    = OFS_RAW + 2457600;      // 128*64*512

// ---------------- K1a: img_mean over 36 regions ----------------
__global__ void k_mean(const float* __restrict__ img, float* __restrict__ mean) {
  const int idx = blockIdx.x * 256 + threadIdx.x;      // 131072 total
  const int i = idx >> 10, l = idx & 1023;
  const float* p = img + (size_t)i * 36 * 1024 + l;
  float s = 0.f;
#pragma unroll
  for (int r = 0; r < 36; ++r) s += p[r * 1024];
  mean[idx] = s * (1.0f / 36.0f);
}

// ---------------- K1b: base = mean @ adapt_W^T + adapt_b ----------------
__global__ void k_base(const float* __restrict__ mean, const float* __restrict__ W,
                       const float* __restrict__ b, float* __restrict__ base) {
  __shared__ float m_s[1024];
  const int i = blockIdx.x, tid = threadIdx.x;   // 128 threads
  for (int k = 0; k < 8; ++k) m_s[tid + 128 * k] = mean[i * 1024 + tid + 128 * k];
  __syncthreads();
  float acc = b[tid];
  const float* wr = W + (size_t)tid * 1024;
#pragma unroll 4
  for (int l = 0; l < 1024; ++l) acc = fmaf(m_s[l], wr[l], acc);
  base[i * 128 + tid] = acc;
}

// ---------------- K2: hypernet GEMM: raw[i][sb+j] = W[j]*base[i] + bvec[j] ----------------
__global__ void __launch_bounds__(256, 4) k_hyper(
    const float* __restrict__ W, const float* __restrict__ bvec,
    const float* __restrict__ base, float* __restrict__ raw, const int J, const int sb) {
  __shared__ float bt[128 * 132];          // base transposed [h][i]
  const int tid = threadIdx.x;
  for (int k = 0; k < 64; ++k) {
    const int idx = tid + 256 * k;         // 16384 = 128i x 128h
    bt[(idx & 127) * 132 + (idx >> 7)] = base[idx];
  }
  __syncthreads();
  const int j0 = blockIdx.x * 64;
  const int ig = tid & 15, jg = tid >> 4;
  const int i0 = ig * 8;
  int jj[4];
#pragma unroll
  for (int r = 0; r < 4; ++r) jj[r] = min(j0 + jg * 4 + r, J - 1);
  const float* w0 = W + (size_t)jj[0] * 128;
  const float* w1 = W + (size_t)jj[1] * 128;
  const float* w2 = W + (size_t)jj[2] * 128;
  const float* w3 = W + (size_t)jj[3] * 128;
  float acc[4][8] = {};
#pragma unroll 4
  for (int h = 0; h < 128; ++h) {
    const float4 bA = *reinterpret_cast<const float4*>(&bt[h * 132 + i0]);
    const float4 bB = *reinterpret_cast<const float4*>(&bt[h * 132 + i0 + 4]);
    const float bv[8] = {bA.x, bA.y, bA.z, bA.w, bB.x, bB.y, bB.z, bB.w};
    const float wv[4] = {w0[h], w1[h], w2[h], w3[h]};
#pragma unroll
    for (int r = 0; r < 4; ++r)
#pragma unroll
      for (int u = 0; u < 8; ++u) acc[r][u] = fmaf(wv[r], bv[u], acc[r][u]);
  }
  const float bb[4] = {bvec[jj[0]], bvec[jj[1]], bvec[jj[2]], bvec[jj[3]]};
  const bool full = (j0 + jg * 4 + 3) < J;
#pragma unroll
  for (int u = 0; u < 8; ++u) {
    float* dst = raw + (size_t)(i0 + u) * 139200 + sb + j0 + jg * 4;
    if (full) {
      *reinterpret_cast<float4*>(dst) = make_float4(acc[0][u] + bb[0], acc[1][u] + bb[1],
                                                    acc[2][u] + bb[2], acc[3][u] + bb[3]);
    } else {
#pragma unroll
      for (int r = 0; r < 4; ++r)
        if (j0 + jg * 4 + r < J) dst[r] = acc[r][u] + bb[r];
    }
  }
}

// ---------------- K2b: stacked conv biases ball[i][o] ----------------
__global__ void k_bias(const float* __restrict__ qbW, const float* __restrict__ qbb,
                       const float* __restrict__ kbW, const float* __restrict__ kbb,
                       const float* __restrict__ vbW, const float* __restrict__ vbb,
                       const float* __restrict__ base, float* __restrict__ ball) {
  __shared__ float bs[128];
  const int i = blockIdx.y, tid = threadIdx.x;
  if (tid < 128) bs[tid] = base[i * 128 + tid];
  __syncthreads();
  const int o = blockIdx.x * 256 + tid;
  if (o >= 464) return;
  const float* Wr = nullptr;
  float bb = 0.0f;
  if (o < 75)                   { Wr = qbW + (size_t)o * 128;         bb = qbb[o]; }
  else if (o >= 80 && o < 155)  { Wr = kbW + (size_t)(o - 80) * 128;  bb = kbb[o - 80]; }
  else if (o >= 160 && o < 460) { Wr = vbW + (size_t)(o - 160) * 128; bb = vbb[o - 160]; }
  float acc = 0.0f;
  if (Wr) {
#pragma unroll 4
    for (int h = 0; h < 128; ++h) acc = fmaf(Wr[h], bs[h], acc);
    acc += bb;
  }
  ball[i * 464 + o] = acc;
}

// ---------------- K3: row-BN (over c) + transpose -> KallT[i][c][o] ----------------
__global__ void k_bnt(const float* __restrict__ raw,
                      const float* __restrict__ qs, const float* __restrict__ qb,
                      const float* __restrict__ ks, const float* __restrict__ kb,
                      const float* __restrict__ vs, const float* __restrict__ vb,
                      float* __restrict__ kallT) {
  __shared__ float scl[64], shf[64];
  __shared__ float tb[32 * 68];
  const int i = blockIdx.y, o0 = blockIdx.x * 64, tid = threadIdx.x;
  const float* rawi = raw + (size_t)i * 139200;
  const int part = tid & 7, og = tid >> 3;   // og 0..31
  for (int p = 0; p < 2; ++p) {
    const int ol = og + 32 * p, og_g = o0 + ol;
    float s = 0.f, b = 0.f;
    bool real = false;
    if (og_g < 75)                     { s = qs[og_g];        b = qb[og_g];        real = true; }
    else if (og_g >= 80 && og_g < 155) { s = ks[og_g - 80];   b = kb[og_g - 80];   real = true; }
    else if (og_g >= 160 && og_g < 460){ s = vs[og_g - 160];  b = vb[og_g - 160];  real = true; }
    const int o_eff = min(og_g, 459);
    const float2* rp = reinterpret_cast<const float2*>(rawi + (size_t)o_eff * 300);
    float s1 = 0.f, s2 = 0.f;
    for (int k = 0; k < 19; ++k) {
      const int q = part + 8 * k;
      if (q < 150) {
        const float2 v = rp[q];
        s1 += v.x + v.y;
        s2 += v.x * v.x + v.y * v.y;
      }
    }
    for (int m = 1; m < 8; m <<= 1) { s1 += __shfl_xor(s1, m); s2 += __shfl_xor(s2, m); }
    const float mu = s1 * (1.0f / 300.0f);
    const float var = s2 * (1.0f / 300.0f) - mu * mu;
    const float scale = real ? s / sqrtf(var + EPSB) : 0.0f;
    const float shift = real ? (b - mu * scale) : 0.0f;
    if (part == 0) { scl[ol] = scale; shf[ol] = shift; }
  }
  __syncthreads();
  for (int cchunk = 0; cchunk < 10; ++cchunk) {
    const int c0 = cchunk * 32;
    for (int p = 0; p < 2; ++p) {
      const int ol = og + 32 * p;
      const int o_eff = min(o0 + ol, 459);
      const float scale = scl[ol], shift = shf[ol];
      const float* rr = rawi + (size_t)o_eff * 300;
#pragma unroll
      for (int k2 = 0; k2 < 2; ++k2) {
        const int cl = (part + 8 * k2) * 2;
        const int c = c0 + cl;
        float2 v = make_float2(0.f, 0.f);
        if (c < 300) v = *reinterpret_cast<const float2*>(&rr[c]);
        tb[cl * 68 + ol] = fmaf(v.x, scale, shift);
        tb[(cl + 1) * 68 + ol] = fmaf(v.y, scale, shift);
      }
    }
    __syncthreads();
    const int ol2 = tid & 63, clb = tid >> 6;
    for (int k3 = 0; k3 < 8; ++k3) {
      const int cl = clb + 4 * k3;
      const int c = c0 + cl, og2 = o0 + ol2;
      if (c < 300 && og2 < 464)
        kallT[(size_t)i * 139200 + (size_t)c * 464 + og2] = tb[cl * 68 + ol2];
    }
    __syncthreads();
  }
}

// ---------------- K4: fused per-(image,caption) attention -> x ----------------
__global__ void __launch_bounds__(320, 4) k_attn(
    const float* __restrict__ cap, const float* __restrict__ kallT,
    const float* __restrict__ ball, const float* __restrict__ gptr,
    float* __restrict__ x_all) {
  __shared__ float cap_s[300 * 36];   // [c][t] pad 36
  __shared__ float qk_s[160 * 36];    // q rows 0..79, k rows 80..159; reused for v chunks
  __shared__ float at_s[32 * 33];     // attn [t][s] pad 33
  const int n = blockIdx.x, i = blockIdx.y, tid = threadIdx.x;
  const float gamma = gptr[0];
  const float* kt = kallT + (size_t)i * 139200;
  const float* bal = ball + i * 464;

  {  // load cap[n] -> cap_s[c][t]
    const float* capn = cap + (size_t)n * 9600;
    for (int k = 0; k < 30; ++k) {
      const int idx = tid + 320 * k;
      const int t = idx / 300, c2 = idx - t * 300;
      cap_s[c2 * 36 + t] = capn[idx];
    }
  }
  __syncthreads();

  {  // phase 1: q,k (160 rows x 32 t), 4o x 4t per thread
    const int tg = tid & 7, og = tid >> 3;   // og 0..39
    const int o0 = og * 4, t0 = tg * 4;
    float acc[4][4];
#pragma unroll
    for (int r = 0; r < 4; ++r) {
      const float bb = bal[o0 + r];
#pragma unroll
      for (int u = 0; u < 4; ++u) acc[r][u] = bb;
    }
#pragma unroll 4
    for (int c2 = 0; c2 < 300; ++c2) {
      const float4 kv = *reinterpret_cast<const float4*>(kt + (size_t)c2 * 464 + o0);
      const float4 cv = *reinterpret_cast<const float4*>(&cap_s[c2 * 36 + t0]);
      const float ak[4] = {kv.x, kv.y, kv.z, kv.w};
      const float av[4] = {cv.x, cv.y, cv.z, cv.w};
#pragma unroll
      for (int r = 0; r < 4; ++r)
#pragma unroll
        for (int u = 0; u < 4; ++u) acc[r][u] = fmaf(ak[r], av[u], acc[r][u]);
    }
#pragma unroll
    for (int r = 0; r < 4; ++r)
      *reinterpret_cast<float4*>(&qk_s[(o0 + r) * 36 + t0]) =
          make_float4(acc[r][0], acc[r][1], acc[r][2], acc[r][3]);
  }
  __syncthreads();

  if (tid < 256) {  // phase 2: scores + softmax over s
    const int sg = tid & 7, t = tid >> 3;
    const int s0 = sg * 4;
    float sc[4] = {0.f, 0.f, 0.f, 0.f};
    for (int o = 0; o < 75; ++o) {
      const float qv = qk_s[o * 36 + t];
      const float4 kv = *reinterpret_cast<const float4*>(&qk_s[(80 + o) * 36 + s0]);
      sc[0] = fmaf(qv, kv.x, sc[0]);
      sc[1] = fmaf(qv, kv.y, sc[1]);
      sc[2] = fmaf(qv, kv.z, sc[2]);
      sc[3] = fmaf(qv, kv.w, sc[3]);
    }
    float m = fmaxf(fmaxf(sc[0], sc[1]), fmaxf(sc[2], sc[3]));
    m = fmaxf(m, __shfl_xor(m, 1));
    m = fmaxf(m, __shfl_xor(m, 2));
    m = fmaxf(m, __shfl_xor(m, 4));
    float e[4], ssum = 0.f;
#pragma unroll
    for (int u = 0; u < 4; ++u) { e[u] = expf(sc[u] - m); ssum += e[u]; }
    ssum += __shfl_xor(ssum, 1);
    ssum += __shfl_xor(ssum, 2);
    ssum += __shfl_xor(ssum, 4);
    const float inv = 1.0f / ssum;
#pragma unroll
    for (int u = 0; u < 4; ++u) at_s[t * 33 + s0 + u] = e[u] * inv;
  }
  __syncthreads();

  const int tl = tid & 15, cc = tid >> 4;   // cc 0..19

  for (int ch = 0; ch < 2; ++ch) {
    const int c0 = ch * 160;
    __syncthreads();  // previous readers of qk_s are done
    {  // 3a: v chunk rows c0..c0+159 (clamped into pad region past 300)
      const int sg = tid & 7, cg = tid >> 3;
      const int vl = cg * 4, s0 = sg * 4;
      const int ob = min(160 + c0 + vl, 460);
      float acc[4][4];
#pragma unroll
      for (int r = 0; r < 4; ++r) {
        const float bb = bal[min(160 + c0 + vl + r, 463)];
#pragma unroll
        for (int u = 0; u < 4; ++u) acc[r][u] = bb;
      }
#pragma unroll 4
      for (int c2 = 0; c2 < 300; ++c2) {
        const float4 kv = *reinterpret_cast<const float4*>(kt + (size_t)c2 * 464 + ob);
        const float4 cv = *reinterpret_cast<const float4*>(&cap_s[c2 * 36 + s0]);
        const float ak[4] = {kv.x, kv.y, kv.z, kv.w};
        const float av[4] = {cv.x, cv.y, cv.z, cv.w};
#pragma unroll
        for (int r = 0; r < 4; ++r)
#pragma unroll
          for (int u = 0; u < 4; ++u) acc[r][u] = fmaf(ak[r], av[u], acc[r][u]);
      }
#pragma unroll
      for (int r = 0; r < 4; ++r)
        *reinterpret_cast<float4*>(&qk_s[(vl + r) * 36 + s0]) =
            make_float4(acc[r][0], acc[r][1], acc[r][2], acc[r][3]);
    }
    __syncthreads();
    {  // 3b: sa = v @ attn^T, residual, max over t
      float a0[32], a1[32];
#pragma unroll
      for (int s = 0; s < 32; ++s) {
        a0[s] = at_s[tl * 33 + s];
        a1[s] = at_s[(tl + 16) * 33 + s];
      }
      const int jn = ch ? 7 : 8;
      for (int j = 0; j < jn; ++j) {
        const int cl = cc + 20 * j;
        const int cgl = c0 + cl;
        float sa0 = 0.0f, sa1 = 0.0f;
#pragma unroll
        for (int sq = 0; sq < 8; ++sq) {
          const float4 v4 = *reinterpret_cast<const float4*>(&qk_s[cl * 36 + sq * 4]);
          const float vv[4] = {v4.x, v4.y, v4.z, v4.w};
#pragma unroll
          for (int u = 0; u < 4; ++u) {
            sa0 = fmaf(vv[u], a0[sq * 4 + u], sa0);
            sa1 = fmaf(vv[u], a1[sq * 4 + u], sa1);
          }
        }
        const float v0 = fmaf(gamma, sa0, cap_s[cgl * 36 + tl]);
        const float v1 = fmaf(gamma, sa1, cap_s[cgl * 36 + tl + 16]);
        float mx = fmaxf(v0, v1);
        mx = fmaxf(mx, __shfl_xor(mx, 1));
        mx = fmaxf(mx, __shfl_xor(mx, 2));
        mx = fmaxf(mx, __shfl_xor(mx, 4));
        mx = fmaxf(mx, __shfl_xor(mx, 8));
        if (tl == 0) x_all[((size_t)i * 64 + n) * 300 + cgl] = mx;
      }
    }
  }
}

// ---------------- K5a: h1 = x @ W1^T + b1 ----------------
__global__ void __launch_bounds__(256, 4) k_h1(
    const float* __restrict__ x_all, const float* __restrict__ W1,
    const float* __restrict__ b1, float* __restrict__ h1) {
  __shared__ float xt[32 * 68];    // [c][n]
  __shared__ float wt[32 * 132];   // [c][e]
  const int ec = blockIdx.x, i = blockIdx.y, tid = threadIdx.x;
  const int e0c = ec * 128;
  const int eg = tid & 15, ng = tid >> 4;
  const int e0 = eg * 8, n0 = ng * 4;
  float acc[4][8] = {};
  for (int cb = 0; cb < 10; ++cb) {
    const int c0 = cb * 32;
    __syncthreads();
    for (int k = 0; k < 8; ++k) {
      const int idx = tid + 256 * k;
      const int nn = idx >> 5, cl = idx & 31;
      const int c = c0 + cl;
      xt[cl * 68 + nn] = (c < 300) ? x_all[((size_t)i * 64 + nn) * 300 + c] : 0.0f;
    }
    for (int k = 0; k < 16; ++k) {
      const int idx = tid + 256 * k;
      const int ee = idx >> 5, cl = idx & 31;
      const int c = c0 + cl;
      wt[cl * 132 + ee] = (c < 300) ? W1[(size_t)(e0c + ee) * 300 + c] : 0.0f;
    }
    __syncthreads();
#pragma unroll 4
    for (int cl = 0; cl < 32; ++cl) {
      const float4 xv = *reinterpret_cast<const float4*>(&xt[cl * 68 + n0]);
      const float4 wa = *reinterpret_cast<const float4*>(&wt[cl * 132 + e0]);
      const float4 wb = *reinterpret_cast<const float4*>(&wt[cl * 132 + e0 + 4]);
      const float xv4[4] = {xv.x, xv.y, xv.z, xv.w};
      const float wv8[8] = {wa.x, wa.y, wa.z, wa.w, wb.x, wb.y, wb.z, wb.w};
#pragma unroll
      for (int u = 0; u < 4; ++u)
#pragma unroll
        for (int v = 0; v < 8; ++v) acc[u][v] = fmaf(xv4[u], wv8[v], acc[u][v]);
    }
  }
  float b1v[8];
#pragma unroll
  for (int v = 0; v < 8; ++v) b1v[v] = b1[e0c + e0 + v];
#pragma unroll
  for (int u = 0; u < 4; ++u) {
    float* dst = h1 + ((size_t)i * 64 + n0 + u) * 512 + e0c + e0;
    *reinterpret_cast<float4*>(dst) =
        make_float4(acc[u][0] + b1v[0], acc[u][1] + b1v[1], acc[u][2] + b1v[2], acc[u][3] + b1v[3]);
    *reinterpret_cast<float4*>(dst + 4) =
        make_float4(acc[u][4] + b1v[4], acc[u][5] + b1v[5], acc[u][6] + b1v[6], acc[u][7] + b1v[7]);
  }
}

// ---------------- K5b: BN1+relu, h2, BN2+relu, out ----------------
__global__ void __launch_bounds__(256) k_mlp(
    const float* __restrict__ h1, const float* __restrict__ bn1s, const float* __restrict__ bn1b,
    const float* __restrict__ W2, const float* __restrict__ b2,
    const float* __restrict__ bn2s, const float* __restrict__ bn2b,
    const float* __restrict__ W3, const float* __restrict__ b3, float* __restrict__ out) {
  __shared__ float h1s[64 * 521];
  __shared__ float h2s[64 * 65];
  const int i = blockIdx.x, tid = threadIdx.x;
  for (int half = 0; half < 2; ++half) {
    const int e = tid + 256 * half;
    float s1 = 0.f, s2 = 0.f;
    for (int nn = 0; nn < 64; ++nn) {
      const float v = h1[((size_t)i * 64 + nn) * 512 + e];
      h1s[nn * 521 + e] = v;
      s1 += v;
      s2 += v * v;
    }
    const float mu = s1 * (1.0f / 64.0f);
    const float var = s2 * (1.0f / 64.0f) - mu * mu;
    const float scale = bn1s[e] / sqrtf(var + EPSB);
    const float shift = bn1b[e] - mu * scale;
    for (int nn = 0; nn < 64; ++nn) {
      const float v = fmaf(h1s[nn * 521 + e], scale, shift);
      h1s[nn * 521 + e] = fmaxf(v, 0.0f);
    }
  }
  __syncthreads();
  {
    const int dg = tid & 15, ng = tid >> 4;
    const int d0 = dg * 4, n0 = ng * 4;
    float acc[4][4] = {};
#pragma unroll 2
    for (int e = 0; e < 512; ++e) {
      float h4[4], w4[4];
#pragma unroll
      for (int u = 0; u < 4; ++u) h4[u] = h1s[(n0 + u) * 521 + e];
#pragma unroll
      for (int v = 0; v < 4; ++v) w4[v] = W2[(size_t)(d0 + v) * 512 + e];
#pragma unroll
      for (int u = 0; u < 4; ++u)
#pragma unroll
        for (int v = 0; v < 4; ++v) acc[u][v] = fmaf(h4[u], w4[v], acc[u][v]);
    }
#pragma unroll
    for (int u = 0; u < 4; ++u)
#pragma unroll
      for (int v = 0; v < 4; ++v) h2s[(n0 + u) * 65 + d0 + v] = acc[u][v] + b2[d0 + v];
  }
  __syncthreads();
  if (tid < 64) {
    const int d = tid;
    float s1 = 0.f, s2 = 0.f;
    for (int nn = 0; nn < 64; ++nn) {
      const float v = h2s[nn * 65 + d];
      s1 += v;
      s2 += v * v;
    }
    const float mu = s1 * (1.0f / 64.0f);
    const float var = s2 * (1.0f / 64.0f) - mu * mu;
    const float scale = bn2s[d] / sqrtf(var + EPSB);
    const float shift = bn2b[d] - mu * scale;
    for (int nn = 0; nn < 64; ++nn)
      h2s[nn * 65 + d] = fmaxf(fmaf(h2s[nn * 65 + d], scale, shift), 0.0f);
  }
  __syncthreads();
  if (tid < 64) {
    const int nn = tid;
    float acc = b3[0];
    for (int d = 0; d < 64; ++d) acc = fmaf(h2s[nn * 65 + d], W3[d], acc);
    out[i * 64 + nn] = acc;
  }
}

extern "C" void kernel_launch(void* const* d_in, const int* in_sizes, int n_in,
                              void* d_out, int out_size, void* d_ws, size_t ws_size,
                              hipStream_t stream) {
  const float* img  = (const float*)d_in[0];
  const float* cap  = (const float*)d_in[1];
  const float* adW  = (const float*)d_in[2];
  const float* adb  = (const float*)d_in[3];
  const float* qkW  = (const float*)d_in[4];
  const float* qkb  = (const float*)d_in[5];
  const float* qbW  = (const float*)d_in[6];
  const float* qbb  = (const float*)d_in[7];
  const float* qbns = (const float*)d_in[8];
  const float* qbnb = (const float*)d_in[9];
  const float* kkW  = (const float*)d_in[10];
  const float* kkb  = (const float*)d_in[11];
  const float* kbW  = (const float*)d_in[12];
  const float* kbb  = (const float*)d_in[13];
  const float* kbns = (const float*)d_in[14];
  const float* kbnb = (const float*)d_in[15];
  const float* vkW  = (const float*)d_in[16];
  const float* vkb  = (const float*)d_in[17];
  const float* vbW  = (const float*)d_in[18];
  const float* vbb  = (const float*)d_in[19];
  const float* vbns = (const float*)d_in[20];
  const float* vbnb = (const float*)d_in[21];
  const float* gamma= (const float*)d_in[22];
  const float* W1   = (const float*)d_in[23];
  const float* b1   = (const float*)d_in[24];
  const float* bn1s = (const float*)d_in[25];
  const float* bn1b = (const float*)d_in[26];
  const float* W2   = (const float*)d_in[27];
  const float* b2   = (const float*)d_in[28];
  const float* bn2s = (const float*)d_in[29];
  const float* bn2b = (const float*)d_in[30];
  const float* W3   = (const float*)d_in[31];
  const float* b3   = (const float*)d_in[32];

  float* ws    = (float*)d_ws;
  float* base  = ws + OFS_BASE;
  float* ball  = ws + OFS_BALL;
  float* mean  = ws + OFS_MEAN;
  float* kallT = ws + OFS_KALLT;
  float* raw   = ws + OFS_RAW;
  float* x_all = ws + OFS_X;     // aliases raw (dead after k_bnt)
  float* h1    = ws + OFS_H1;
  float* out   = (float*)d_out;

  k_mean<<<512, 256, 0, stream>>>(img, mean);
  k_base<<<128, 128, 0, stream>>>(mean, adW, adb, base);
  k_hyper<<<352, 256, 0, stream>>>(qkW, qkb, base, raw, 22500, 0);
  k_hyper<<<352, 256, 0, stream>>>(kkW, kkb, base, raw, 22500, 24000);
  k_hyper<<<1407, 256, 0, stream>>>(vkW, vkb, base, raw, 90000, 48000);
  k_bias<<<dim3(2, 128), 256, 0, stream>>>(qbW, qbb, kbW, kbb, vbW, vbb, base, ball);
  k_bnt<<<dim3(8, 128), 256, 0, stream>>>(raw, qbns, qbnb, kbns, kbnb, vbns, vbnb, kallT);
  k_attn<<<dim3(64, 128), 320, 0, stream>>>(cap, kallT, ball, gamma, x_all);
  k_h1<<<dim3(4, 128), 256, 0, stream>>>(x_all, W1, b1, h1);
  k_mlp<<<128, 256, 0, stream>>>(h1, bn1s, bn1b, W2, b2, bn2s, bn2b, W3, b3, out);
}

// Round 2
// 1557.633 us; speedup vs baseline: 2.0464x; 2.0464x over previous
//
#include <hip/hip_runtime.h>
#include <math.h>

#define EPSB 1e-5f

// Bi=128 Bc=64 T=32 C=300 OQK=75 H=128 LAT=1024
// Padded stacked o-dim (512): q [0,96) (75 real), k [96,192) (75 real), v [192,512) (300 real)
// c padded 300 -> 320.
// ws layout (float offsets):
static const long OFS_BASE  = 0;                      // 128*128
static const long OFS_BALL  = 16384;                  // 128*512
static const long OFS_MEAN  = 81920;                  // 128*1024
static const long OFS_CAPB  = 212992;                 // 2*64*32*320 ushort = 655360 floats
static const long OFS_RAWP  = 868352;                 // 128*512*320 fp32 -> becomes bf16 hi|lo in place
static const long OFS_X     = 21839872;               // 128*64*300
static const long OFS_H1    = OFS_RAWP;               // alias (Kall dead after k_attn2)

using bf16x8 = __attribute__((ext_vector_type(8))) __bf16;
using f32x4  = __attribute__((ext_vector_type(4))) float;
#define MFMA16(a, b, c) __builtin_amdgcn_mfma_f32_16x16x32_bf16(a, b, c, 0, 0, 0)

__device__ inline ushort f2bf(float f) {
  const unsigned u = __float_as_uint(f);
  return (ushort)((u + 0x7FFFu + ((u >> 16) & 1u)) >> 16);
}
__device__ inline float bf2f(ushort h) { return __uint_as_float(((unsigned)h) << 16); }

// ---------------- K1a: img_mean over 36 regions ----------------
__global__ void k_mean(const float* __restrict__ img, float* __restrict__ mean) {
  const int idx = blockIdx.x * 256 + threadIdx.x;      // 131072 total
  const int i = idx >> 10, l = idx & 1023;
  const float* p = img + (size_t)i * 36 * 1024 + l;
  float s = 0.f;
#pragma unroll
  for (int r = 0; r < 36; ++r) s += p[r * 1024];
  mean[idx] = s * (1.0f / 36.0f);
}

// ---------------- K1b: base = mean @ adapt_W^T + adapt_b ----------------
__global__ void k_base(const float* __restrict__ mean, const float* __restrict__ W,
                       const float* __restrict__ b, float* __restrict__ base) {
  __shared__ float m_s[1024];
  const int i = blockIdx.x, tid = threadIdx.x;   // 128 threads
  for (int k = 0; k < 8; ++k) m_s[tid + 128 * k] = mean[i * 1024 + tid + 128 * k];
  __syncthreads();
  float acc = b[tid];
  const float* wr = W + (size_t)tid * 1024;
#pragma unroll 4
  for (int l = 0; l < 1024; ++l) acc = fmaf(m_s[l], wr[l], acc);
  base[i * 128 + tid] = acc;
}

// ---------------- K2: hypernet GEMM into padded rawP [i][512][320] ----------------
__global__ void __launch_bounds__(256, 4) k_hyper(
    const float* __restrict__ W, const float* __restrict__ bvec,
    const float* __restrict__ base, float* __restrict__ rawP, const int J, const int R0) {
  __shared__ float bt[128 * 132];          // base transposed [h][i]
  const int tid = threadIdx.x;
  for (int k = 0; k < 64; ++k) {
    const int idx = tid + 256 * k;         // 16384 = 128i x 128h
    bt[(idx & 127) * 132 + (idx >> 7)] = base[idx];
  }
  __syncthreads();
  const int j0 = blockIdx.x * 64;
  const int ig = tid & 15, jg = tid >> 4;
  const int i0 = ig * 8;
  int jj[4];
#pragma unroll
  for (int r = 0; r < 4; ++r) jj[r] = min(j0 + jg * 4 + r, J - 1);
  const float* w0 = W + (size_t)jj[0] * 128;
  const float* w1 = W + (size_t)jj[1] * 128;
  const float* w2 = W + (size_t)jj[2] * 128;
  const float* w3 = W + (size_t)jj[3] * 128;
  float acc[4][8] = {};
#pragma unroll 4
  for (int h = 0; h < 128; ++h) {
    const float4 bA = *reinterpret_cast<const float4*>(&bt[h * 132 + i0]);
    const float4 bB = *reinterpret_cast<const float4*>(&bt[h * 132 + i0 + 4]);
    const float bv[8] = {bA.x, bA.y, bA.z, bA.w, bB.x, bB.y, bB.z, bB.w};
    const float wv[4] = {w0[h], w1[h], w2[h], w3[h]};
#pragma unroll
    for (int r = 0; r < 4; ++r)
#pragma unroll
      for (int u = 0; u < 8; ++u) acc[r][u] = fmaf(wv[r], bv[u], acc[r][u]);
  }
  const float bb[4] = {bvec[jj[0]], bvec[jj[1]], bvec[jj[2]], bvec[jj[3]]};
#pragma unroll
  for (int u = 0; u < 8; ++u) {
    float* rp = rawP + ((size_t)(i0 + u) * 512 + R0) * 320;
#pragma unroll
    for (int r = 0; r < 4; ++r) {
      const int jr = j0 + jg * 4 + r;
      if (jr < J) {
        const int o = jr / 300, c = jr - o * 300;
        rp[o * 320 + c] = acc[r][u] + bb[r];
      }
    }
  }
}

// ---------------- K2b: stacked conv biases ball[i][512] ----------------
__global__ void k_bias(const float* __restrict__ qbW, const float* __restrict__ qbb,
                       const float* __restrict__ kbW, const float* __restrict__ kbb,
                       const float* __restrict__ vbW, const float* __restrict__ vbb,
                       const float* __restrict__ base, float* __restrict__ ball) {
  __shared__ float bs[128];
  const int i = blockIdx.y, tid = threadIdx.x;
  if (tid < 128) bs[tid] = base[i * 128 + tid];
  __syncthreads();
  const int o = blockIdx.x * 256 + tid;
  if (o >= 512) return;
  const float* Wr = nullptr;
  float bb = 0.0f;
  if (o < 75)                   { Wr = qbW + (size_t)o * 128;         bb = qbb[o]; }
  else if (o >= 96 && o < 171)  { Wr = kbW + (size_t)(o - 96) * 128;  bb = kbb[o - 96]; }
  else if (o >= 192 && o < 492) { Wr = vbW + (size_t)(o - 192) * 128; bb = vbb[o - 192]; }
  float acc = 0.0f;
  if (Wr) {
#pragma unroll 4
    for (int h = 0; h < 128; ++h) acc = fmaf(Wr[h], bs[h], acc);
    acc += bb;
  }
  ball[i * 512 + o] = acc;
}

// ---------------- K2c: cap -> split-bf16 capB (hi plane then lo plane), [n][t][320] ----------------
__global__ void k_capb(const float* __restrict__ cap, ushort* __restrict__ capB) {
  const int idx = blockIdx.x * 256 + threadIdx.x;   // 655360
  if (idx >= 64 * 32 * 320) return;
  const int c = idx % 320;
  const int nt = idx / 320;
  float v = 0.f;
  if (c < 300) v = cap[nt * 300 + c];
  const ushort hi = f2bf(v);
  capB[idx] = hi;
  capB[655360 + idx] = f2bf(v - bf2f(hi));
}

// ---------------- K3: row-BN + in-place fp32 -> bf16 hi|lo split ----------------
// One wave per row of rawP [i][512][320]. Row bytes 1280 == 320+320 ushort.
__global__ void __launch_bounds__(256) k_bnt2(float* __restrict__ rawP,
    const float* __restrict__ qs, const float* __restrict__ qb,
    const float* __restrict__ ks_, const float* __restrict__ kb_,
    const float* __restrict__ vs, const float* __restrict__ vb) {
  const int tid = threadIdx.x, lane = tid & 63, w = tid >> 6;
  const int rg = blockIdx.x * 4 + w;        // 0 .. 65535
  const int o = rg & 511;
  float* row = rawP + (size_t)rg * 320;
  ushort* urow = reinterpret_cast<ushort*>(row);
  float s = 0.f, b = 0.f;
  bool real = false;
  if (o < 75)                    { s = qs[o];       b = qb[o];       real = true; }
  else if (o >= 96 && o < 171)   { s = ks_[o - 96]; b = kb_[o - 96]; real = true; }
  else if (o >= 192 && o < 492)  { s = vs[o - 192]; b = vb[o - 192]; real = true; }
  if (!real) {
    for (int k = 0; k < 10; ++k) urow[lane + 64 * k] = 0;
    return;
  }
  float x[5], s1 = 0.f, s2 = 0.f;
#pragma unroll
  for (int k = 0; k < 5; ++k) {
    const int c = lane + 64 * k;
    x[k] = (c < 300) ? row[c] : 0.f;
    s1 += x[k];
    s2 += x[k] * x[k];
  }
  for (int m = 1; m < 64; m <<= 1) { s1 += __shfl_xor(s1, m); s2 += __shfl_xor(s2, m); }
  const float mu = s1 * (1.0f / 300.0f);
  const float var = s2 * (1.0f / 300.0f) - mu * mu;
  const float scale = s / sqrtf(var + EPSB);
  const float shift = b - mu * scale;
#pragma unroll
  for (int k = 0; k < 5; ++k) {
    const int c = lane + 64 * k;
    const float val = (c < 300) ? fmaf(x[k], scale, shift) : 0.f;
    const ushort hi = f2bf(val);
    urow[c] = hi;
    urow[320 + c] = f2bf(val - bf2f(hi));
  }
}

// ---------------- K4: fused per-(image,caption) attention, MFMA projections ----------------
__global__ void __launch_bounds__(256, 4) k_attn2(
    const float* __restrict__ cap, const ushort* __restrict__ kall,
    const ushort* __restrict__ capB, const float* __restrict__ ball,
    const float* __restrict__ gptr, float* __restrict__ x_all) {
  __shared__ float qk_s[192 * 36];   // q rows 0-95, k rows 96-191; reused as v chunk buffer
  __shared__ float at_s[32 * 36];
  const int n = blockIdx.x, i = blockIdx.y, tid = threadIdx.x;
  const int lane = tid & 63, w = tid >> 6;
  const int lrow = lane & 15, kg = lane >> 4;
  const float gamma = gptr[0];
  const ushort* kbi = kall + (size_t)i * 512 * 640;   // per row: 320 hi then 320 lo
  const ushort* cbh = capB + (size_t)n * 32 * 320;
  const ushort* cbl = cbh + (size_t)64 * 32 * 320;
  const float* bal = ball + i * 512;

  // ---- P1: q+k rows [0,192), wave w owns rows [48w, 48w+48)
  {
    f32x4 acc[3][2];
#pragma unroll
    for (int a = 0; a < 3; ++a)
#pragma unroll
      for (int b2 = 0; b2 < 2; ++b2) acc[a][b2] = (f32x4){0.f, 0.f, 0.f, 0.f};
#pragma unroll 2
    for (int ks = 0; ks < 10; ++ks) {
      const int c0 = ks * 32 + kg * 8;
      bf16x8 Bh[2], Bl[2];
#pragma unroll
      for (int nt = 0; nt < 2; ++nt) {
        const int t = nt * 16 + lrow;
        Bh[nt] = *reinterpret_cast<const bf16x8*>(cbh + t * 320 + c0);
        Bl[nt] = *reinterpret_cast<const bf16x8*>(cbl + t * 320 + c0);
      }
#pragma unroll
      for (int mt = 0; mt < 3; ++mt) {
        const int o = w * 48 + mt * 16 + lrow;
        const ushort* rp = kbi + (size_t)o * 640;
        const bf16x8 Ah = *reinterpret_cast<const bf16x8*>(rp + c0);
        const bf16x8 Al = *reinterpret_cast<const bf16x8*>(rp + c0 + 320);
#pragma unroll
        for (int nt = 0; nt < 2; ++nt) {
          acc[mt][nt] = MFMA16(Ah, Bh[nt], acc[mt][nt]);
          acc[mt][nt] = MFMA16(Ah, Bl[nt], acc[mt][nt]);
          acc[mt][nt] = MFMA16(Al, Bh[nt], acc[mt][nt]);
        }
      }
    }
#pragma unroll
    for (int mt = 0; mt < 3; ++mt)
#pragma unroll
      for (int nt = 0; nt < 2; ++nt)
#pragma unroll
        for (int r = 0; r < 4; ++r) {
          const int o = w * 48 + mt * 16 + kg * 4 + r;
          qk_s[o * 36 + nt * 16 + lrow] = acc[mt][nt][r] + bal[o];
        }
  }
  __syncthreads();

  // ---- P2: scores + softmax (fp32 VALU)
  {
    const int sg = tid & 7, tq = tid >> 3;
    const int s0 = sg * 4;
    float sc[4] = {0.f, 0.f, 0.f, 0.f};
    for (int o = 0; o < 75; ++o) {
      const float qv = qk_s[o * 36 + tq];
      const float4 kv = *reinterpret_cast<const float4*>(&qk_s[(96 + o) * 36 + s0]);
      sc[0] = fmaf(qv, kv.x, sc[0]);
      sc[1] = fmaf(qv, kv.y, sc[1]);
      sc[2] = fmaf(qv, kv.z, sc[2]);
      sc[3] = fmaf(qv, kv.w, sc[3]);
    }
    float m = fmaxf(fmaxf(sc[0], sc[1]), fmaxf(sc[2], sc[3]));
    m = fmaxf(m, __shfl_xor(m, 1));
    m = fmaxf(m, __shfl_xor(m, 2));
    m = fmaxf(m, __shfl_xor(m, 4));
    float e[4], ssum = 0.f;
#pragma unroll
    for (int u = 0; u < 4; ++u) { e[u] = expf(sc[u] - m); ssum += e[u]; }
    ssum += __shfl_xor(ssum, 1);
    ssum += __shfl_xor(ssum, 2);
    ssum += __shfl_xor(ssum, 4);
    const float inv = 1.0f / ssum;
#pragma unroll
    for (int u = 0; u < 4; ++u) at_s[tq * 36 + s0 + u] = e[u] * inv;
  }
  __syncthreads();

  // ---- P3: v in 3 chunks of up to 128 rows (v rows [192,512), real c < 300)
  for (int ch = 0; ch < 3; ++ch) {
    const int RB = 192 + ch * 128;
    const int nmt = (ch < 2) ? 2 : 1;     // m-tiles per wave this chunk
    f32x4 vacc[2][2];
#pragma unroll
    for (int a = 0; a < 2; ++a)
#pragma unroll
      for (int b2 = 0; b2 < 2; ++b2) vacc[a][b2] = (f32x4){0.f, 0.f, 0.f, 0.f};
#pragma unroll 2
    for (int ks = 0; ks < 10; ++ks) {
      const int c0 = ks * 32 + kg * 8;
      bf16x8 Bh[2], Bl[2];
#pragma unroll
      for (int nt = 0; nt < 2; ++nt) {
        const int t = nt * 16 + lrow;
        Bh[nt] = *reinterpret_cast<const bf16x8*>(cbh + t * 320 + c0);
        Bl[nt] = *reinterpret_cast<const bf16x8*>(cbl + t * 320 + c0);
      }
      for (int mi = 0; mi < nmt; ++mi) {
        const int o = RB + (w + mi * 4) * 16 + lrow;
        const ushort* rp = kbi + (size_t)o * 640;
        const bf16x8 Ah = *reinterpret_cast<const bf16x8*>(rp + c0);
        const bf16x8 Al = *reinterpret_cast<const bf16x8*>(rp + c0 + 320);
#pragma unroll
        for (int nt = 0; nt < 2; ++nt) {
          vacc[mi][nt] = MFMA16(Ah, Bh[nt], vacc[mi][nt]);
          vacc[mi][nt] = MFMA16(Ah, Bl[nt], vacc[mi][nt]);
          vacc[mi][nt] = MFMA16(Al, Bh[nt], vacc[mi][nt]);
        }
      }
    }
    if (ch) __syncthreads();   // prior 3b readers of v buffer done
    for (int mi = 0; mi < nmt; ++mi)
#pragma unroll
      for (int nt = 0; nt < 2; ++nt)
#pragma unroll
        for (int r = 0; r < 4; ++r) {
          const int vl = (w + mi * 4) * 16 + kg * 4 + r;
          qk_s[vl * 36 + nt * 16 + lrow] = vacc[mi][nt][r] + bal[RB + vl];
        }
    __syncthreads();
    // 3b: sa = v @ attn^T, residual, max over t
    {
      const int tl = tid & 15, cc = tid >> 4;
      float a0[32], a1[32];
#pragma unroll
      for (int s2 = 0; s2 < 32; ++s2) {
        a0[s2] = at_s[tl * 36 + s2];
        a1[s2] = at_s[(tl + 16) * 36 + s2];
      }
      const int jn = (ch < 2) ? 8 : 4;
      for (int j = 0; j < jn; ++j) {
        const int cl = cc + 16 * j;
        const int cgl = ch * 128 + cl;
        if (cgl < 300) {
          float sa0 = 0.f, sa1 = 0.f;
#pragma unroll
          for (int sq = 0; sq < 8; ++sq) {
            const float4 v4 = *reinterpret_cast<const float4*>(&qk_s[cl * 36 + sq * 4]);
            const float vv[4] = {v4.x, v4.y, v4.z, v4.w};
#pragma unroll
            for (int u = 0; u < 4; ++u) {
              sa0 = fmaf(vv[u], a0[sq * 4 + u], sa0);
              sa1 = fmaf(vv[u], a1[sq * 4 + u], sa1);
            }
          }
          const float v0 = fmaf(gamma, sa0, cap[(size_t)n * 9600 + tl * 300 + cgl]);
          const float v1 = fmaf(gamma, sa1, cap[(size_t)n * 9600 + (tl + 16) * 300 + cgl]);
          float mx = fmaxf(v0, v1);
          mx = fmaxf(mx, __shfl_xor(mx, 1));
          mx = fmaxf(mx, __shfl_xor(mx, 2));
          mx = fmaxf(mx, __shfl_xor(mx, 4));
          mx = fmaxf(mx, __shfl_xor(mx, 8));
          if (tl == 0) x_all[((size_t)i * 64 + n) * 300 + cgl] = mx;
        }
      }
    }
  }
}

// ---------------- K5a: h1 = x @ W1^T + b1 ----------------
__global__ void __launch_bounds__(256, 4) k_h1(
    const float* __restrict__ x_all, const float* __restrict__ W1,
    const float* __restrict__ b1, float* __restrict__ h1) {
  __shared__ float xt[32 * 68];    // [c][n]
  __shared__ float wt[32 * 132];   // [c][e]
  const int ec = blockIdx.x, i = blockIdx.y, tid = threadIdx.x;
  const int e0c = ec * 128;
  const int eg = tid & 15, ng = tid >> 4;
  const int e0 = eg * 8, n0 = ng * 4;
  float acc[4][8] = {};
  for (int cb = 0; cb < 10; ++cb) {
    const int c0 = cb * 32;
    __syncthreads();
    for (int k = 0; k < 8; ++k) {
      const int idx = tid + 256 * k;
      const int nn = idx >> 5, cl = idx & 31;
      const int c = c0 + cl;
      xt[cl * 68 + nn] = (c < 300) ? x_all[((size_t)i * 64 + nn) * 300 + c] : 0.0f;
    }
    for (int k = 0; k < 16; ++k) {
      const int idx = tid + 256 * k;
      const int ee = idx >> 5, cl = idx & 31;
      const int c = c0 + cl;
      wt[cl * 132 + ee] = (c < 300) ? W1[(size_t)(e0c + ee) * 300 + c] : 0.0f;
    }
    __syncthreads();
#pragma unroll 4
    for (int cl = 0; cl < 32; ++cl) {
      const float4 xv = *reinterpret_cast<const float4*>(&xt[cl * 68 + n0]);
      const float4 wa = *reinterpret_cast<const float4*>(&wt[cl * 132 + e0]);
      const float4 wb = *reinterpret_cast<const float4*>(&wt[cl * 132 + e0 + 4]);
      const float xv4[4] = {xv.x, xv.y, xv.z, xv.w};
      const float wv8[8] = {wa.x, wa.y, wa.z, wa.w, wb.x, wb.y, wb.z, wb.w};
#pragma unroll
      for (int u = 0; u < 4; ++u)
#pragma unroll
        for (int v = 0; v < 8; ++v) acc[u][v] = fmaf(xv4[u], wv8[v], acc[u][v]);
    }
  }
  float b1v[8];
#pragma unroll
  for (int v = 0; v < 8; ++v) b1v[v] = b1[e0c + e0 + v];
#pragma unroll
  for (int u = 0; u < 4; ++u) {
    float* dst = h1 + ((size_t)i * 64 + n0 + u) * 512 + e0c + e0;
    *reinterpret_cast<float4*>(dst) =
        make_float4(acc[u][0] + b1v[0], acc[u][1] + b1v[1], acc[u][2] + b1v[2], acc[u][3] + b1v[3]);
    *reinterpret_cast<float4*>(dst + 4) =
        make_float4(acc[u][4] + b1v[4], acc[u][5] + b1v[5], acc[u][6] + b1v[6], acc[u][7] + b1v[7]);
  }
}

// ---------------- K5b: BN1+relu, h2, BN2+relu, out ----------------
__global__ void __launch_bounds__(256) k_mlp(
    const float* __restrict__ h1, const float* __restrict__ bn1s, const float* __restrict__ bn1b,
    const float* __restrict__ W2, const float* __restrict__ b2,
    const float* __restrict__ bn2s, const float* __restrict__ bn2b,
    const float* __restrict__ W3, const float* __restrict__ b3, float* __restrict__ out) {
  __shared__ float h1s[64 * 521];
  __shared__ float h2s[64 * 65];
  const int i = blockIdx.x, tid = threadIdx.x;
  for (int half = 0; half < 2; ++half) {
    const int e = tid + 256 * half;
    float s1 = 0.f, s2 = 0.f;
    for (int nn = 0; nn < 64; ++nn) {
      const float v = h1[((size_t)i * 64 + nn) * 512 + e];
      h1s[nn * 521 + e] = v;
      s1 += v;
      s2 += v * v;
    }
    const float mu = s1 * (1.0f / 64.0f);
    const float var = s2 * (1.0f / 64.0f) - mu * mu;
    const float scale = bn1s[e] / sqrtf(var + EPSB);
    const float shift = bn1b[e] - mu * scale;
    for (int nn = 0; nn < 64; ++nn) {
      const float v = fmaf(h1s[nn * 521 + e], scale, shift);
      h1s[nn * 521 + e] = fmaxf(v, 0.0f);
    }
  }
  __syncthreads();
  {
    const int dg = tid & 15, ng = tid >> 4;
    const int d0 = dg * 4, n0 = ng * 4;
    float acc[4][4] = {};
#pragma unroll 2
    for (int e = 0; e < 512; ++e) {
      float h4[4], w4[4];
#pragma unroll
      for (int u = 0; u < 4; ++u) h4[u] = h1s[(n0 + u) * 521 + e];
#pragma unroll
      for (int v = 0; v < 4; ++v) w4[v] = W2[(size_t)(d0 + v) * 512 + e];
#pragma unroll
      for (int u = 0; u < 4; ++u)
#pragma unroll
        for (int v = 0; v < 4; ++v) acc[u][v] = fmaf(h4[u], w4[v], acc[u][v]);
    }
#pragma unroll
    for (int u = 0; u < 4; ++u)
#pragma unroll
      for (int v = 0; v < 4; ++v) h2s[(n0 + u) * 65 + d0 + v] = acc[u][v] + b2[d0 + v];
  }
  __syncthreads();
  if (tid < 64) {
    const int d = tid;
    float s1 = 0.f, s2 = 0.f;
    for (int nn = 0; nn < 64; ++nn) {
      const float v = h2s[nn * 65 + d];
      s1 += v;
      s2 += v * v;
    }
    const float mu = s1 * (1.0f / 64.0f);
    const float var = s2 * (1.0f / 64.0f) - mu * mu;
    const float scale = bn2s[d] / sqrtf(var + EPSB);
    const float shift = bn2b[d] - mu * scale;
    for (int nn = 0; nn < 64; ++nn)
      h2s[nn * 65 + d] = fmaxf(fmaf(h2s[nn * 65 + d], scale, shift), 0.0f);
  }
  __syncthreads();
  if (tid < 64) {
    const int nn = tid;
    float acc = b3[0];
    for (int d = 0; d < 64; ++d) acc = fmaf(h2s[nn * 65 + d], W3[d], acc);
    out[i * 64 + nn] = acc;
  }
}

extern "C" void kernel_launch(void* const* d_in, const int* in_sizes, int n_in,
                              void* d_out, int out_size, void* d_ws, size_t ws_size,
                              hipStream_t stream) {
  const float* img  = (const float*)d_in[0];
  const float* cap  = (const float*)d_in[1];
  const float* adW  = (const float*)d_in[2];
  const float* adb  = (const float*)d_in[3];
  const float* qkW  = (const float*)d_in[4];
  const float* qkb  = (const float*)d_in[5];
  const float* qbW  = (const float*)d_in[6];
  const float* qbb  = (const float*)d_in[7];
  const float* qbns = (const float*)d_in[8];
  const float* qbnb = (const float*)d_in[9];
  const float* kkW  = (const float*)d_in[10];
  const float* kkb  = (const float*)d_in[11];
  const float* kbW  = (const float*)d_in[12];
  const float* kbb  = (const float*)d_in[13];
  const float* kbns = (const float*)d_in[14];
  const float* kbnb = (const float*)d_in[15];
  const float* vkW  = (const float*)d_in[16];
  const float* vkb  = (const float*)d_in[17];
  const float* vbW  = (const float*)d_in[18];
  const float* vbb  = (const float*)d_in[19];
  const float* vbns = (const float*)d_in[20];
  const float* vbnb = (const float*)d_in[21];
  const float* gamma= (const float*)d_in[22];
  const float* W1   = (const float*)d_in[23];
  const float* b1   = (const float*)d_in[24];
  const float* bn1s = (const float*)d_in[25];
  const float* bn1b = (const float*)d_in[26];
  const float* W2   = (const float*)d_in[27];
  const float* b2   = (const float*)d_in[28];
  const float* bn2s = (const float*)d_in[29];
  const float* bn2b = (const float*)d_in[30];
  const float* W3   = (const float*)d_in[31];
  const float* b3   = (const float*)d_in[32];

  float* ws    = (float*)d_ws;
  float* base  = ws + OFS_BASE;
  float* ball  = ws + OFS_BALL;
  float* mean  = ws + OFS_MEAN;
  ushort* capB = (ushort*)(ws + OFS_CAPB);
  float* rawP  = ws + OFS_RAWP;
  ushort* kall = (ushort*)(ws + OFS_RAWP);
  float* x_all = ws + OFS_X;
  float* h1    = ws + OFS_H1;    // aliases rawP/kall (dead after k_attn2)
  float* out   = (float*)d_out;

  k_mean<<<512, 256, 0, stream>>>(img, mean);
  k_base<<<128, 128, 0, stream>>>(mean, adW, adb, base);
  k_hyper<<<352, 256, 0, stream>>>(qkW, qkb, base, rawP, 22500, 0);
  k_hyper<<<352, 256, 0, stream>>>(kkW, kkb, base, rawP, 22500, 96);
  k_hyper<<<1407, 256, 0, stream>>>(vkW, vkb, base, rawP, 90000, 192);
  k_bias<<<dim3(2, 128), 256, 0, stream>>>(qbW, qbb, kbW, kbb, vbW, vbb, base, ball);
  k_capb<<<2560, 256, 0, stream>>>(cap, capB);
  k_bnt2<<<16384, 256, 0, stream>>>(rawP, qbns, qbnb, kbns, kbnb, vbns, vbnb);
  k_attn2<<<dim3(64, 128), 256, 0, stream>>>(cap, kall, capB, ball, gamma, x_all);
  k_h1<<<dim3(4, 128), 256, 0, stream>>>(x_all, W1, b1, h1);
  k_mlp<<<128, 256, 0, stream>>>(h1, bn1s, bn1b, W2, b2, bn2s, bn2b, W3, b3, out);
}

// Round 3
// 1110.130 us; speedup vs baseline: 2.8713x; 1.4031x over previous
//
#include <hip/hip_runtime.h>
#include <math.h>

#define EPSB 1e-5f

// Bi=128 Bc=64 T=32 C=300 OQK=75 H=128 LAT=1024
// Padded stacked o-dim (512): q [0,96) (75 real), k [96,192) (75 real), v [192,512) (300 real)
// c padded 300 -> 320.
// ws layout (float offsets):
static const long OFS_BASE  = 0;                      // 128*128
static const long OFS_BALL  = 16384;                  // 128*512
static const long OFS_MEAN  = 81920;                  // 128*1024
static const long OFS_CAPB  = 212992;                 // 2*64*32*320 ushort = 655360 floats
static const long OFS_RAWP  = 868352;                 // 128*512*320 fp32 -> becomes bf16 hi|lo in place
static const long OFS_X     = 21839872;               // 128*64*300
static const long OFS_H1    = OFS_RAWP;               // alias (Kall dead after k_attn3)

using bf16x8 = __attribute__((ext_vector_type(8))) __bf16;
using f32x4  = __attribute__((ext_vector_type(4))) float;
#define MFMA16(a, b, c) __builtin_amdgcn_mfma_f32_16x16x32_bf16(a, b, c, 0, 0, 0)

__device__ inline ushort f2bf(float f) {
  const unsigned u = __float_as_uint(f);
  return (ushort)((u + 0x7FFFu + ((u >> 16) & 1u)) >> 16);
}
__device__ inline float bf2f(ushort h) { return __uint_as_float(((unsigned)h) << 16); }

// ---------------- K1a: img_mean over 36 regions ----------------
__global__ void k_mean(const float* __restrict__ img, float* __restrict__ mean) {
  const int idx = blockIdx.x * 256 + threadIdx.x;      // 131072 total
  const int i = idx >> 10, l = idx & 1023;
  const float* p = img + (size_t)i * 36 * 1024 + l;
  float s = 0.f;
#pragma unroll
  for (int r = 0; r < 36; ++r) s += p[r * 1024];
  mean[idx] = s * (1.0f / 36.0f);
}

// ---------------- K1b: base = mean @ adapt_W^T + adapt_b ----------------
__global__ void k_base(const float* __restrict__ mean, const float* __restrict__ W,
                       const float* __restrict__ b, float* __restrict__ base) {
  __shared__ float m_s[1024];
  const int i = blockIdx.x, tid = threadIdx.x;   // 128 threads
  for (int k = 0; k < 8; ++k) m_s[tid + 128 * k] = mean[i * 1024 + tid + 128 * k];
  __syncthreads();
  float acc = b[tid];
  const float* wr = W + (size_t)tid * 1024;
#pragma unroll 4
  for (int l = 0; l < 1024; ++l) acc = fmaf(m_s[l], wr[l], acc);
  base[i * 128 + tid] = acc;
}

// ---------------- K2: hypernet GEMM into padded rawP [i][512][320] ----------------
__global__ void __launch_bounds__(256, 4) k_hyper(
    const float* __restrict__ W, const float* __restrict__ bvec,
    const float* __restrict__ base, float* __restrict__ rawP, const int J, const int R0) {
  __shared__ float bt[128 * 132];          // base transposed [h][i]
  const int tid = threadIdx.x;
  for (int k = 0; k < 64; ++k) {
    const int idx = tid + 256 * k;         // 16384 = 128i x 128h
    bt[(idx & 127) * 132 + (idx >> 7)] = base[idx];
  }
  __syncthreads();
  const int j0 = blockIdx.x * 64;
  const int ig = tid & 15, jg = tid >> 4;
  const int i0 = ig * 8;
  int jj[4];
#pragma unroll
  for (int r = 0; r < 4; ++r) jj[r] = min(j0 + jg * 4 + r, J - 1);
  const float* w0 = W + (size_t)jj[0] * 128;
  const float* w1 = W + (size_t)jj[1] * 128;
  const float* w2 = W + (size_t)jj[2] * 128;
  const float* w3 = W + (size_t)jj[3] * 128;
  float acc[4][8] = {};
#pragma unroll 4
  for (int h = 0; h < 128; ++h) {
    const float4 bA = *reinterpret_cast<const float4*>(&bt[h * 132 + i0]);
    const float4 bB = *reinterpret_cast<const float4*>(&bt[h * 132 + i0 + 4]);
    const float bv[8] = {bA.x, bA.y, bA.z, bA.w, bB.x, bB.y, bB.z, bB.w};
    const float wv[4] = {w0[h], w1[h], w2[h], w3[h]};
#pragma unroll
    for (int r = 0; r < 4; ++r)
#pragma unroll
      for (int u = 0; u < 8; ++u) acc[r][u] = fmaf(wv[r], bv[u], acc[r][u]);
  }
  const float bb[4] = {bvec[jj[0]], bvec[jj[1]], bvec[jj[2]], bvec[jj[3]]};
#pragma unroll
  for (int u = 0; u < 8; ++u) {
    float* rp = rawP + ((size_t)(i0 + u) * 512 + R0) * 320;
#pragma unroll
    for (int r = 0; r < 4; ++r) {
      const int jr = j0 + jg * 4 + r;
      if (jr < J) {
        const int o = jr / 300, c = jr - o * 300;
        rp[o * 320 + c] = acc[r][u] + bb[r];
      }
    }
  }
}

// ---------------- K2b: stacked conv biases ball[i][512] ----------------
__global__ void k_bias(const float* __restrict__ qbW, const float* __restrict__ qbb,
                       const float* __restrict__ kbW, const float* __restrict__ kbb,
                       const float* __restrict__ vbW, const float* __restrict__ vbb,
                       const float* __restrict__ base, float* __restrict__ ball) {
  __shared__ float bs[128];
  const int i = blockIdx.y, tid = threadIdx.x;
  if (tid < 128) bs[tid] = base[i * 128 + tid];
  __syncthreads();
  const int o = blockIdx.x * 256 + tid;
  if (o >= 512) return;
  const float* Wr = nullptr;
  float bb = 0.0f;
  if (o < 75)                   { Wr = qbW + (size_t)o * 128;         bb = qbb[o]; }
  else if (o >= 96 && o < 171)  { Wr = kbW + (size_t)(o - 96) * 128;  bb = kbb[o - 96]; }
  else if (o >= 192 && o < 492) { Wr = vbW + (size_t)(o - 192) * 128; bb = vbb[o - 192]; }
  float acc = 0.0f;
  if (Wr) {
#pragma unroll 4
    for (int h = 0; h < 128; ++h) acc = fmaf(Wr[h], bs[h], acc);
    acc += bb;
  }
  ball[i * 512 + o] = acc;
}

// ---------------- K2c: cap -> split-bf16 capB (hi plane then lo plane), [n][t][320] ----------------
__global__ void k_capb(const float* __restrict__ cap, ushort* __restrict__ capB) {
  const int idx = blockIdx.x * 256 + threadIdx.x;   // 655360
  if (idx >= 64 * 32 * 320) return;
  const int c = idx % 320;
  const int nt = idx / 320;
  float v = 0.f;
  if (c < 300) v = cap[nt * 300 + c];
  const ushort hi = f2bf(v);
  capB[idx] = hi;
  capB[655360 + idx] = f2bf(v - bf2f(hi));
}

// ---------------- K3: row-BN + in-place fp32 -> bf16 hi|lo split ----------------
// One wave per row of rawP [i][512][320]. Row bytes 1280 == 320+320 ushort.
__global__ void __launch_bounds__(256) k_bnt2(float* __restrict__ rawP,
    const float* __restrict__ qs, const float* __restrict__ qb,
    const float* __restrict__ ks_, const float* __restrict__ kb_,
    const float* __restrict__ vs, const float* __restrict__ vb) {
  const int tid = threadIdx.x, lane = tid & 63, w = tid >> 6;
  const int rg = blockIdx.x * 4 + w;        // 0 .. 65535
  const int o = rg & 511;
  float* row = rawP + (size_t)rg * 320;
  ushort* urow = reinterpret_cast<ushort*>(row);
  float s = 0.f, b = 0.f;
  bool real = false;
  if (o < 75)                    { s = qs[o];       b = qb[o];       real = true; }
  else if (o >= 96 && o < 171)   { s = ks_[o - 96]; b = kb_[o - 96]; real = true; }
  else if (o >= 192 && o < 492)  { s = vs[o - 192]; b = vb[o - 192]; real = true; }
  if (!real) {
    for (int k = 0; k < 10; ++k) urow[lane + 64 * k] = 0;
    return;
  }
  float x[5], s1 = 0.f, s2 = 0.f;
#pragma unroll
  for (int k = 0; k < 5; ++k) {
    const int c = lane + 64 * k;
    x[k] = (c < 300) ? row[c] : 0.f;
    s1 += x[k];
    s2 += x[k] * x[k];
  }
  for (int m = 1; m < 64; m <<= 1) { s1 += __shfl_xor(s1, m); s2 += __shfl_xor(s2, m); }
  const float mu = s1 * (1.0f / 300.0f);
  const float var = s2 * (1.0f / 300.0f) - mu * mu;
  const float scale = s / sqrtf(var + EPSB);
  const float shift = b - mu * scale;
#pragma unroll
  for (int k = 0; k < 5; ++k) {
    const int c = lane + 64 * k;
    const float val = (c < 300) ? fmaf(x[k], scale, shift) : 0.f;
    const ushort hi = f2bf(val);
    urow[c] = hi;
    urow[320 + c] = f2bf(val - bf2f(hi));
  }
}

// ---------------- K4: fused per-(image,caption) attention, MFMA projections ----------------
// q/k: 3-pass split-bf16 (score precision). v: 1-pass bf16 (error analysis: ~2.4e-3 relative,
// renormalized by each BN; final contribution ~1-3e-3 abs vs 18.8e-3 threshold).
__global__ void __launch_bounds__(256, 5) k_attn3(
    const float* __restrict__ cap, const ushort* __restrict__ kall,
    const ushort* __restrict__ capB, const float* __restrict__ ball,
    const float* __restrict__ gptr, float* __restrict__ x_all) {
  __shared__ float qk_s[192 * 36];   // q rows 0-95, k rows 96-191; reused as v chunk buffer
  __shared__ float at_s[32 * 36];
  const int n = blockIdx.x, i = blockIdx.y, tid = threadIdx.x;
  const int lane = tid & 63, w = tid >> 6;
  const int lrow = lane & 15, kg = lane >> 4;
  const float gamma = gptr[0];
  const ushort* kbi = kall + (size_t)i * 512 * 640;   // per row: 320 hi then 320 lo
  const ushort* cbh = capB + (size_t)n * 32 * 320;
  const ushort* cbl = cbh + (size_t)64 * 32 * 320;
  const float* bal = ball + i * 512;

  // ---- P1: q+k rows [0,192), wave w owns rows [48w, 48w+48); batch all loads per k-step
  {
    f32x4 acc[3][2];
#pragma unroll
    for (int a = 0; a < 3; ++a)
#pragma unroll
      for (int b2 = 0; b2 < 2; ++b2) acc[a][b2] = (f32x4){0.f, 0.f, 0.f, 0.f};
#pragma unroll 2
    for (int ks = 0; ks < 10; ++ks) {
      const int c0 = ks * 32 + kg * 8;
      bf16x8 Bh[2], Bl[2], Ah[3], Al[3];
#pragma unroll
      for (int nt = 0; nt < 2; ++nt) {
        const int t = nt * 16 + lrow;
        Bh[nt] = *reinterpret_cast<const bf16x8*>(cbh + t * 320 + c0);
        Bl[nt] = *reinterpret_cast<const bf16x8*>(cbl + t * 320 + c0);
      }
#pragma unroll
      for (int mt = 0; mt < 3; ++mt) {
        const int o = w * 48 + mt * 16 + lrow;
        const ushort* rp = kbi + (size_t)o * 640;
        Ah[mt] = *reinterpret_cast<const bf16x8*>(rp + c0);
        Al[mt] = *reinterpret_cast<const bf16x8*>(rp + c0 + 320);
      }
#pragma unroll
      for (int mt = 0; mt < 3; ++mt)
#pragma unroll
        for (int nt = 0; nt < 2; ++nt) {
          acc[mt][nt] = MFMA16(Ah[mt], Bh[nt], acc[mt][nt]);
          acc[mt][nt] = MFMA16(Ah[mt], Bl[nt], acc[mt][nt]);
          acc[mt][nt] = MFMA16(Al[mt], Bh[nt], acc[mt][nt]);
        }
    }
#pragma unroll
    for (int mt = 0; mt < 3; ++mt)
#pragma unroll
      for (int nt = 0; nt < 2; ++nt)
#pragma unroll
        for (int r = 0; r < 4; ++r) {
          const int o = w * 48 + mt * 16 + kg * 4 + r;
          qk_s[o * 36 + nt * 16 + lrow] = acc[mt][nt][r] + bal[o];
        }
  }
  __syncthreads();

  // ---- P2: scores + softmax (fp32 VALU)
  {
    const int sg = tid & 7, tq = tid >> 3;
    const int s0 = sg * 4;
    float sc[4] = {0.f, 0.f, 0.f, 0.f};
    for (int o = 0; o < 75; ++o) {
      const float qv = qk_s[o * 36 + tq];
      const float4 kv = *reinterpret_cast<const float4*>(&qk_s[(96 + o) * 36 + s0]);
      sc[0] = fmaf(qv, kv.x, sc[0]);
      sc[1] = fmaf(qv, kv.y, sc[1]);
      sc[2] = fmaf(qv, kv.z, sc[2]);
      sc[3] = fmaf(qv, kv.w, sc[3]);
    }
    float m = fmaxf(fmaxf(sc[0], sc[1]), fmaxf(sc[2], sc[3]));
    m = fmaxf(m, __shfl_xor(m, 1));
    m = fmaxf(m, __shfl_xor(m, 2));
    m = fmaxf(m, __shfl_xor(m, 4));
    float e[4], ssum = 0.f;
#pragma unroll
    for (int u = 0; u < 4; ++u) { e[u] = expf(sc[u] - m); ssum += e[u]; }
    ssum += __shfl_xor(ssum, 1);
    ssum += __shfl_xor(ssum, 2);
    ssum += __shfl_xor(ssum, 4);
    const float inv = 1.0f / ssum;
#pragma unroll
    for (int u = 0; u < 4; ++u) at_s[tq * 36 + s0 + u] = e[u] * inv;
  }
  __syncthreads();

  // ---- P3: v rows [192,512) in 2 chunks {192,128}; 1-pass bf16
  for (int ch = 0; ch < 2; ++ch) {
    const int RB = 192 + ch * 192;
    const int nmt = ch ? 2 : 3;
    f32x4 vacc[3][2];
#pragma unroll
    for (int a = 0; a < 3; ++a)
#pragma unroll
      for (int b2 = 0; b2 < 2; ++b2) vacc[a][b2] = (f32x4){0.f, 0.f, 0.f, 0.f};
#pragma unroll 2
    for (int ks = 0; ks < 10; ++ks) {
      const int c0 = ks * 32 + kg * 8;
      bf16x8 Bh[2], Av[3];
#pragma unroll
      for (int nt = 0; nt < 2; ++nt)
        Bh[nt] = *reinterpret_cast<const bf16x8*>(cbh + (nt * 16 + lrow) * 320 + c0);
      for (int mi = 0; mi < nmt; ++mi) {
        const int o = RB + (w + mi * 4) * 16 + lrow;
        Av[mi] = *reinterpret_cast<const bf16x8*>(kbi + (size_t)o * 640 + c0);
      }
      for (int mi = 0; mi < nmt; ++mi)
#pragma unroll
        for (int nt = 0; nt < 2; ++nt)
          vacc[mi][nt] = MFMA16(Av[mi], Bh[nt], vacc[mi][nt]);
    }
    if (ch) __syncthreads();   // prior 3b readers of v buffer done
    for (int mi = 0; mi < nmt; ++mi)
#pragma unroll
      for (int nt = 0; nt < 2; ++nt)
#pragma unroll
        for (int r = 0; r < 4; ++r) {
          const int vl = (w + mi * 4) * 16 + kg * 4 + r;
          qk_s[vl * 36 + nt * 16 + lrow] = vacc[mi][nt][r] + bal[RB + vl];
        }
    __syncthreads();
    // 3b: sa = v @ attn^T, residual, max over t
    {
      const int tl = tid & 15, cc = tid >> 4;
      float a0[32], a1[32];
#pragma unroll
      for (int s2 = 0; s2 < 32; ++s2) {
        a0[s2] = at_s[tl * 36 + s2];
        a1[s2] = at_s[(tl + 16) * 36 + s2];
      }
      const int jn = ch ? 7 : 12;
      for (int j = 0; j < jn; ++j) {
        const int cl = cc + 16 * j;
        const int cgl = ch * 192 + cl;
        if (cgl < 300) {
          float sa0 = 0.f, sa1 = 0.f;
#pragma unroll
          for (int sq = 0; sq < 8; ++sq) {
            const float4 v4 = *reinterpret_cast<const float4*>(&qk_s[cl * 36 + sq * 4]);
            const float vv[4] = {v4.x, v4.y, v4.z, v4.w};
#pragma unroll
            for (int u = 0; u < 4; ++u) {
              sa0 = fmaf(vv[u], a0[sq * 4 + u], sa0);
              sa1 = fmaf(vv[u], a1[sq * 4 + u], sa1);
            }
          }
          const float v0 = fmaf(gamma, sa0, cap[(size_t)n * 9600 + tl * 300 + cgl]);
          const float v1 = fmaf(gamma, sa1, cap[(size_t)n * 9600 + (tl + 16) * 300 + cgl]);
          float mx = fmaxf(v0, v1);
          mx = fmaxf(mx, __shfl_xor(mx, 1));
          mx = fmaxf(mx, __shfl_xor(mx, 2));
          mx = fmaxf(mx, __shfl_xor(mx, 4));
          mx = fmaxf(mx, __shfl_xor(mx, 8));
          if (tl == 0) x_all[((size_t)i * 64 + n) * 300 + cgl] = mx;
        }
      }
    }
  }
}

// ---------------- K5a: h1 = x @ W1^T + b1 ----------------
__global__ void __launch_bounds__(256, 4) k_h1(
    const float* __restrict__ x_all, const float* __restrict__ W1,
    const float* __restrict__ b1, float* __restrict__ h1) {
  __shared__ float xt[32 * 68];    // [c][n]
  __shared__ float wt[32 * 132];   // [c][e]
  const int ec = blockIdx.x, i = blockIdx.y, tid = threadIdx.x;
  const int e0c = ec * 128;
  const int eg = tid & 15, ng = tid >> 4;
  const int e0 = eg * 8, n0 = ng * 4;
  float acc[4][8] = {};
  for (int cb = 0; cb < 10; ++cb) {
    const int c0 = cb * 32;
    __syncthreads();
    for (int k = 0; k < 8; ++k) {
      const int idx = tid + 256 * k;
      const int nn = idx >> 5, cl = idx & 31;
      const int c = c0 + cl;
      xt[cl * 68 + nn] = (c < 300) ? x_all[((size_t)i * 64 + nn) * 300 + c] : 0.0f;
    }
    for (int k = 0; k < 16; ++k) {
      const int idx = tid + 256 * k;
      const int ee = idx >> 5, cl = idx & 31;
      const int c = c0 + cl;
      wt[cl * 132 + ee] = (c < 300) ? W1[(size_t)(e0c + ee) * 300 + c] : 0.0f;
    }
    __syncthreads();
#pragma unroll 4
    for (int cl = 0; cl < 32; ++cl) {
      const float4 xv = *reinterpret_cast<const float4*>(&xt[cl * 68 + n0]);
      const float4 wa = *reinterpret_cast<const float4*>(&wt[cl * 132 + e0]);
      const float4 wb = *reinterpret_cast<const float4*>(&wt[cl * 132 + e0 + 4]);
      const float xv4[4] = {xv.x, xv.y, xv.z, xv.w};
      const float wv8[8] = {wa.x, wa.y, wa.z, wa.w, wb.x, wb.y, wb.z, wb.w};
#pragma unroll
      for (int u = 0; u < 4; ++u)
#pragma unroll
        for (int v = 0; v < 8; ++v) acc[u][v] = fmaf(xv4[u], wv8[v], acc[u][v]);
    }
  }
  float b1v[8];
#pragma unroll
  for (int v = 0; v < 8; ++v) b1v[v] = b1[e0c + e0 + v];
#pragma unroll
  for (int u = 0; u < 4; ++u) {
    float* dst = h1 + ((size_t)i * 64 + n0 + u) * 512 + e0c + e0;
    *reinterpret_cast<float4*>(dst) =
        make_float4(acc[u][0] + b1v[0], acc[u][1] + b1v[1], acc[u][2] + b1v[2], acc[u][3] + b1v[3]);
    *reinterpret_cast<float4*>(dst + 4) =
        make_float4(acc[u][4] + b1v[4], acc[u][5] + b1v[5], acc[u][6] + b1v[6], acc[u][7] + b1v[7]);
  }
}

// ---------------- K5b: BN1+relu, h2, BN2+relu, out ----------------
__global__ void __launch_bounds__(256) k_mlp(
    const float* __restrict__ h1, const float* __restrict__ bn1s, const float* __restrict__ bn1b,
    const float* __restrict__ W2, const float* __restrict__ b2,
    const float* __restrict__ bn2s, const float* __restrict__ bn2b,
    const float* __restrict__ W3, const float* __restrict__ b3, float* __restrict__ out) {
  __shared__ float h1s[64 * 521];
  __shared__ float h2s[64 * 65];
  const int i = blockIdx.x, tid = threadIdx.x;
  for (int half = 0; half < 2; ++half) {
    const int e = tid + 256 * half;
    float s1 = 0.f, s2 = 0.f;
    for (int nn = 0; nn < 64; ++nn) {
      const float v = h1[((size_t)i * 64 + nn) * 512 + e];
      h1s[nn * 521 + e] = v;
      s1 += v;
      s2 += v * v;
    }
    const float mu = s1 * (1.0f / 64.0f);
    const float var = s2 * (1.0f / 64.0f) - mu * mu;
    const float scale = bn1s[e] / sqrtf(var + EPSB);
    const float shift = bn1b[e] - mu * scale;
    for (int nn = 0; nn < 64; ++nn) {
      const float v = fmaf(h1s[nn * 521 + e], scale, shift);
      h1s[nn * 521 + e] = fmaxf(v, 0.0f);
    }
  }
  __syncthreads();
  {
    const int dg = tid & 15, ng = tid >> 4;
    const int d0 = dg * 4, n0 = ng * 4;
    float acc[4][4] = {};
#pragma unroll 2
    for (int e = 0; e < 512; ++e) {
      float h4[4], w4[4];
#pragma unroll
      for (int u = 0; u < 4; ++u) h4[u] = h1s[(n0 + u) * 521 + e];
#pragma unroll
      for (int v = 0; v < 4; ++v) w4[v] = W2[(size_t)(d0 + v) * 512 + e];
#pragma unroll
      for (int u = 0; u < 4; ++u)
#pragma unroll
        for (int v = 0; v < 4; ++v) acc[u][v] = fmaf(h4[u], w4[v], acc[u][v]);
    }
#pragma unroll
    for (int u = 0; u < 4; ++u)
#pragma unroll
      for (int v = 0; v < 4; ++v) h2s[(n0 + u) * 65 + d0 + v] = acc[u][v] + b2[d0 + v];
  }
  __syncthreads();
  if (tid < 64) {
    const int d = tid;
    float s1 = 0.f, s2 = 0.f;
    for (int nn = 0; nn < 64; ++nn) {
      const float v = h2s[nn * 65 + d];
      s1 += v;
      s2 += v * v;
    }
    const float mu = s1 * (1.0f / 64.0f);
    const float var = s2 * (1.0f / 64.0f) - mu * mu;
    const float scale = bn2s[d] / sqrtf(var + EPSB);
    const float shift = bn2b[d] - mu * scale;
    for (int nn = 0; nn < 64; ++nn)
      h2s[nn * 65 + d] = fmaxf(fmaf(h2s[nn * 65 + d], scale, shift), 0.0f);
  }
  __syncthreads();
  if (tid < 64) {
    const int nn = tid;
    float acc = b3[0];
    for (int d = 0; d < 64; ++d) acc = fmaf(h2s[nn * 65 + d], W3[d], acc);
    out[i * 64 + nn] = acc;
  }
}

extern "C" void kernel_launch(void* const* d_in, const int* in_sizes, int n_in,
                              void* d_out, int out_size, void* d_ws, size_t ws_size,
                              hipStream_t stream) {
  const float* img  = (const float*)d_in[0];
  const float* cap  = (const float*)d_in[1];
  const float* adW  = (const float*)d_in[2];
  const float* adb  = (const float*)d_in[3];
  const float* qkW  = (const float*)d_in[4];
  const float* qkb  = (const float*)d_in[5];
  const float* qbW  = (const float*)d_in[6];
  const float* qbb  = (const float*)d_in[7];
  const float* qbns = (const float*)d_in[8];
  const float* qbnb = (const float*)d_in[9];
  const float* kkW  = (const float*)d_in[10];
  const float* kkb  = (const float*)d_in[11];
  const float* kbW  = (const float*)d_in[12];
  const float* kbb  = (const float*)d_in[13];
  const float* kbns = (const float*)d_in[14];
  const float* kbnb = (const float*)d_in[15];
  const float* vkW  = (const float*)d_in[16];
  const float* vkb  = (const float*)d_in[17];
  const float* vbW  = (const float*)d_in[18];
  const float* vbb  = (const float*)d_in[19];
  const float* vbns = (const float*)d_in[20];
  const float* vbnb = (const float*)d_in[21];
  const float* gamma= (const float*)d_in[22];
  const float* W1   = (const float*)d_in[23];
  const float* b1   = (const float*)d_in[24];
  const float* bn1s = (const float*)d_in[25];
  const float* bn1b = (const float*)d_in[26];
  const float* W2   = (const float*)d_in[27];
  const float* b2   = (const float*)d_in[28];
  const float* bn2s = (const float*)d_in[29];
  const float* bn2b = (const float*)d_in[30];
  const float* W3   = (const float*)d_in[31];
  const float* b3   = (const float*)d_in[32];

  float* ws    = (float*)d_ws;
  float* base  = ws + OFS_BASE;
  float* ball  = ws + OFS_BALL;
  float* mean  = ws + OFS_MEAN;
  ushort* capB = (ushort*)(ws + OFS_CAPB);
  float* rawP  = ws + OFS_RAWP;
  ushort* kall = (ushort*)(ws + OFS_RAWP);
  float* x_all = ws + OFS_X;
  float* h1    = ws + OFS_H1;    // aliases rawP/kall (dead after k_attn3)
  float* out   = (float*)d_out;

  k_mean<<<512, 256, 0, stream>>>(img, mean);
  k_base<<<128, 128, 0, stream>>>(mean, adW, adb, base);
  k_hyper<<<352, 256, 0, stream>>>(qkW, qkb, base, rawP, 22500, 0);
  k_hyper<<<352, 256, 0, stream>>>(kkW, kkb, base, rawP, 22500, 96);
  k_hyper<<<1407, 256, 0, stream>>>(vkW, vkb, base, rawP, 90000, 192);
  k_bias<<<dim3(2, 128), 256, 0, stream>>>(qbW, qbb, kbW, kbb, vbW, vbb, base, ball);
  k_capb<<<2560, 256, 0, stream>>>(cap, capB);
  k_bnt2<<<16384, 256, 0, stream>>>(rawP, qbns, qbnb, kbns, kbnb, vbns, vbnb);
  k_attn3<<<dim3(64, 128), 256, 0, stream>>>(cap, kall, capB, ball, gamma, x_all);
  k_h1<<<dim3(4, 128), 256, 0, stream>>>(x_all, W1, b1, h1);
  k_mlp<<<128, 256, 0, stream>>>(h1, bn1s, bn1b, W2, b2, bn2s, bn2b, W3, b3, out);
}

// Round 4
// 1096.349 us; speedup vs baseline: 2.9074x; 1.0126x over previous
//
#include <hip/hip_runtime.h>
#include <math.h>

#define EPSB 1e-5f

// Bi=128 Bc=64 T=32 C=300 OQK=75 H=128 LAT=1024
// Padded stacked o-dim (512): q [0,96) (75 real), k [96,192) (75 real), v [192,512) (300 real)
// c padded 300 -> 320.
// ws layout (float offsets):
static const long OFS_BASE  = 0;                      // 128*128
static const long OFS_BALL  = 16384;                  // 128*512
static const long OFS_MEAN  = 81920;                  // 128*1024
static const long OFS_CAPB  = 212992;                 // 2*64*32*320 ushort = 655360 floats
static const long OFS_RAWP  = 868352;                 // 128*512*320 fp32 -> becomes bf16 hi|lo in place
static const long OFS_X     = 21839872;               // 128*64*300
static const long OFS_H1    = OFS_RAWP;               // alias (Kall dead after k_attn4)

using bf16x8 = __attribute__((ext_vector_type(8))) __bf16;
using f32x4  = __attribute__((ext_vector_type(4))) float;
#define MFMA16(a, b, c) __builtin_amdgcn_mfma_f32_16x16x32_bf16(a, b, c, 0, 0, 0)

__device__ inline ushort f2bf(float f) {
  const unsigned u = __float_as_uint(f);
  return (ushort)((u + 0x7FFFu + ((u >> 16) & 1u)) >> 16);
}
__device__ inline float bf2f(ushort h) { return __uint_as_float(((unsigned)h) << 16); }

// ---------------- K1a: img_mean over 36 regions ----------------
__global__ void k_mean(const float* __restrict__ img, float* __restrict__ mean) {
  const int idx = blockIdx.x * 256 + threadIdx.x;      // 131072 total
  const int i = idx >> 10, l = idx & 1023;
  const float* p = img + (size_t)i * 36 * 1024 + l;
  float s = 0.f;
#pragma unroll
  for (int r = 0; r < 36; ++r) s += p[r * 1024];
  mean[idx] = s * (1.0f / 36.0f);
}

// ---------------- K1b: base = mean @ adapt_W^T + adapt_b ----------------
__global__ void k_base(const float* __restrict__ mean, const float* __restrict__ W,
                       const float* __restrict__ b, float* __restrict__ base) {
  __shared__ float m_s[1024];
  const int i = blockIdx.x, tid = threadIdx.x;   // 128 threads
  for (int k = 0; k < 8; ++k) m_s[tid + 128 * k] = mean[i * 1024 + tid + 128 * k];
  __syncthreads();
  float acc = b[tid];
  const float* wr = W + (size_t)tid * 1024;
#pragma unroll 4
  for (int l = 0; l < 1024; ++l) acc = fmaf(m_s[l], wr[l], acc);
  base[i * 128 + tid] = acc;
}

// ---------------- K2: hypernet GEMM into padded rawP [i][512][320] ----------------
__global__ void __launch_bounds__(256, 4) k_hyper(
    const float* __restrict__ W, const float* __restrict__ bvec,
    const float* __restrict__ base, float* __restrict__ rawP, const int J, const int R0) {
  __shared__ float bt[128 * 132];          // base transposed [h][i]
  const int tid = threadIdx.x;
  for (int k = 0; k < 64; ++k) {
    const int idx = tid + 256 * k;         // 16384 = 128i x 128h
    bt[(idx & 127) * 132 + (idx >> 7)] = base[idx];
  }
  __syncthreads();
  const int j0 = blockIdx.x * 64;
  const int ig = tid & 15, jg = tid >> 4;
  const int i0 = ig * 8;
  int jj[4];
#pragma unroll
  for (int r = 0; r < 4; ++r) jj[r] = min(j0 + jg * 4 + r, J - 1);
  const float* w0 = W + (size_t)jj[0] * 128;
  const float* w1 = W + (size_t)jj[1] * 128;
  const float* w2 = W + (size_t)jj[2] * 128;
  const float* w3 = W + (size_t)jj[3] * 128;
  float acc[4][8] = {};
#pragma unroll 4
  for (int h = 0; h < 128; ++h) {
    const float4 bA = *reinterpret_cast<const float4*>(&bt[h * 132 + i0]);
    const float4 bB = *reinterpret_cast<const float4*>(&bt[h * 132 + i0 + 4]);
    const float bv[8] = {bA.x, bA.y, bA.z, bA.w, bB.x, bB.y, bB.z, bB.w};
    const float wv[4] = {w0[h], w1[h], w2[h], w3[h]};
#pragma unroll
    for (int r = 0; r < 4; ++r)
#pragma unroll
      for (int u = 0; u < 8; ++u) acc[r][u] = fmaf(wv[r], bv[u], acc[r][u]);
  }
  const float bb[4] = {bvec[jj[0]], bvec[jj[1]], bvec[jj[2]], bvec[jj[3]]};
  const int jbase = j0 + jg * 4;
  if (jbase + 3 < J) {
    const int o = jbase / 300, c = jbase - o * 300;
    if (c <= 296) {   // all 4 in one row; c%4==0 (300%4==0) -> aligned float4
#pragma unroll
      for (int u = 0; u < 8; ++u) {
        float* rp = rawP + ((size_t)(i0 + u) * 512 + R0) * 320;
        *reinterpret_cast<float4*>(rp + o * 320 + c) =
            make_float4(acc[0][u] + bb[0], acc[1][u] + bb[1], acc[2][u] + bb[2], acc[3][u] + bb[3]);
      }
    } else {
#pragma unroll
      for (int u = 0; u < 8; ++u) {
        float* rp = rawP + ((size_t)(i0 + u) * 512 + R0) * 320;
#pragma unroll
        for (int r = 0; r < 4; ++r) {
          const int jr = jbase + r;
          const int o2 = jr / 300, c2 = jr - o2 * 300;
          rp[o2 * 320 + c2] = acc[r][u] + bb[r];
        }
      }
    }
  } else {
#pragma unroll
    for (int u = 0; u < 8; ++u) {
      float* rp = rawP + ((size_t)(i0 + u) * 512 + R0) * 320;
#pragma unroll
      for (int r = 0; r < 4; ++r) {
        const int jr = jbase + r;
        if (jr < J) {
          const int o2 = jr / 300, c2 = jr - o2 * 300;
          rp[o2 * 320 + c2] = acc[r][u] + bb[r];
        }
      }
    }
  }
}

// ---------------- K2b: stacked conv biases ball[i][512] ----------------
__global__ void k_bias(const float* __restrict__ qbW, const float* __restrict__ qbb,
                       const float* __restrict__ kbW, const float* __restrict__ kbb,
                       const float* __restrict__ vbW, const float* __restrict__ vbb,
                       const float* __restrict__ base, float* __restrict__ ball) {
  __shared__ float bs[128];
  const int i = blockIdx.y, tid = threadIdx.x;
  if (tid < 128) bs[tid] = base[i * 128 + tid];
  __syncthreads();
  const int o = blockIdx.x * 256 + tid;
  if (o >= 512) return;
  const float* Wr = nullptr;
  float bb = 0.0f;
  if (o < 75)                   { Wr = qbW + (size_t)o * 128;         bb = qbb[o]; }
  else if (o >= 96 && o < 171)  { Wr = kbW + (size_t)(o - 96) * 128;  bb = kbb[o - 96]; }
  else if (o >= 192 && o < 492) { Wr = vbW + (size_t)(o - 192) * 128; bb = vbb[o - 192]; }
  float acc = 0.0f;
  if (Wr) {
#pragma unroll 4
    for (int h = 0; h < 128; ++h) acc = fmaf(Wr[h], bs[h], acc);
    acc += bb;
  }
  ball[i * 512 + o] = acc;
}

// ---------------- K2c: cap -> split-bf16 capB (hi plane then lo plane), [n][t][320] ----------------
__global__ void k_capb(const float* __restrict__ cap, ushort* __restrict__ capB) {
  const int idx = blockIdx.x * 256 + threadIdx.x;   // 655360
  if (idx >= 64 * 32 * 320) return;
  const int c = idx % 320;
  const int nt = idx / 320;
  float v = 0.f;
  if (c < 300) v = cap[nt * 300 + c];
  const ushort hi = f2bf(v);
  capB[idx] = hi;
  capB[655360 + idx] = f2bf(v - bf2f(hi));
}

// ---------------- K3: row-BN + in-place fp32 -> bf16 hi|lo split ----------------
__global__ void __launch_bounds__(256) k_bnt2(float* __restrict__ rawP,
    const float* __restrict__ qs, const float* __restrict__ qb,
    const float* __restrict__ ks_, const float* __restrict__ kb_,
    const float* __restrict__ vs, const float* __restrict__ vb) {
  const int tid = threadIdx.x, lane = tid & 63, w = tid >> 6;
  const int rg = blockIdx.x * 4 + w;        // 0 .. 65535
  const int o = rg & 511;
  float* row = rawP + (size_t)rg * 320;
  ushort* urow = reinterpret_cast<ushort*>(row);
  float s = 0.f, b = 0.f;
  bool real = false;
  if (o < 75)                    { s = qs[o];       b = qb[o];       real = true; }
  else if (o >= 96 && o < 171)   { s = ks_[o - 96]; b = kb_[o - 96]; real = true; }
  else if (o >= 192 && o < 492)  { s = vs[o - 192]; b = vb[o - 192]; real = true; }
  if (!real) {
    for (int k = 0; k < 10; ++k) urow[lane + 64 * k] = 0;
    return;
  }
  float x[5], s1 = 0.f, s2 = 0.f;
#pragma unroll
  for (int k = 0; k < 5; ++k) {
    const int c = lane + 64 * k;
    x[k] = (c < 300) ? row[c] : 0.f;
    s1 += x[k];
    s2 += x[k] * x[k];
  }
  for (int m = 1; m < 64; m <<= 1) { s1 += __shfl_xor(s1, m); s2 += __shfl_xor(s2, m); }
  const float mu = s1 * (1.0f / 300.0f);
  const float var = s2 * (1.0f / 300.0f) - mu * mu;
  const float scale = s / sqrtf(var + EPSB);
  const float shift = b - mu * scale;
#pragma unroll
  for (int k = 0; k < 5; ++k) {
    const int c = lane + 64 * k;
    const float val = (c < 300) ? fmaf(x[k], scale, shift) : 0.f;
    const ushort hi = f2bf(val);
    urow[c] = hi;
    urow[320 + c] = f2bf(val - bf2f(hi));
  }
}

// ---------------- K4: fused attention; software-pipelined MFMA + unrolled VALU ----------------
// q/k: 3-pass split-bf16 (score precision). v: 1-pass bf16.
__global__ void __launch_bounds__(256, 4) k_attn4(
    const float* __restrict__ cap, const ushort* __restrict__ kall,
    const ushort* __restrict__ capB, const float* __restrict__ ball,
    const float* __restrict__ gptr, float* __restrict__ x_all) {
  __shared__ float qk_s[192 * 36];   // q rows 0-95, k rows 96-191; reused as v chunk buffer
  __shared__ float at_s[32 * 36];
  const int n = blockIdx.x, i = blockIdx.y, tid = threadIdx.x;
  const int lane = tid & 63, w = tid >> 6;
  const int lrow = lane & 15, kg = lane >> 4;
  const float gamma = gptr[0];
  const ushort* kbi = kall + (size_t)i * 512 * 640;   // per row: 320 hi then 320 lo
  const ushort* cbh = capB + (size_t)n * 32 * 320;
  const ushort* cbl = cbh + (size_t)64 * 32 * 320;
  const float* bal = ball + i * 512;

  // ---- P1: q+k rows [0,192), wave w owns rows [48w,48w+48); 2-deep A-prefetch pipeline
  {
    f32x4 acc[3][2];
#pragma unroll
    for (int a = 0; a < 3; ++a)
#pragma unroll
      for (int b2 = 0; b2 < 2; ++b2) acc[a][b2] = (f32x4){0.f, 0.f, 0.f, 0.f};
    const ushort* rp0 = kbi + (size_t)(w * 48 + lrow) * 640;
    bf16x8 AhA[3], AlA[3], AhB[3], AlB[3];
    {  // preload kstep 0
      const int c0 = kg * 8;
#pragma unroll
      for (int mt = 0; mt < 3; ++mt) {
        const ushort* rp = rp0 + mt * 16 * 640;
        AhA[mt] = *reinterpret_cast<const bf16x8*>(rp + c0);
        AlA[mt] = *reinterpret_cast<const bf16x8*>(rp + c0 + 320);
      }
    }
#pragma unroll
    for (int kp = 0; kp < 5; ++kp) {
      {  // even kstep 2kp: consume A-set A; prefetch 2kp+1 into B
        const int c0 = (2 * kp) * 32 + kg * 8;
        bf16x8 Bh[2], Bl[2];
#pragma unroll
        for (int nt = 0; nt < 2; ++nt) {
          const int t = nt * 16 + lrow;
          Bh[nt] = *reinterpret_cast<const bf16x8*>(cbh + t * 320 + c0);
          Bl[nt] = *reinterpret_cast<const bf16x8*>(cbl + t * 320 + c0);
        }
        const int c1 = c0 + 32;
#pragma unroll
        for (int mt = 0; mt < 3; ++mt) {
          const ushort* rp = rp0 + mt * 16 * 640;
          AhB[mt] = *reinterpret_cast<const bf16x8*>(rp + c1);
          AlB[mt] = *reinterpret_cast<const bf16x8*>(rp + c1 + 320);
        }
#pragma unroll
        for (int mt = 0; mt < 3; ++mt)
#pragma unroll
          for (int nt = 0; nt < 2; ++nt) {
            acc[mt][nt] = MFMA16(AhA[mt], Bh[nt], acc[mt][nt]);
            acc[mt][nt] = MFMA16(AhA[mt], Bl[nt], acc[mt][nt]);
            acc[mt][nt] = MFMA16(AlA[mt], Bh[nt], acc[mt][nt]);
          }
      }
      {  // odd kstep 2kp+1: consume A-set B; prefetch 2kp+2 into A
        const int c0 = (2 * kp + 1) * 32 + kg * 8;
        bf16x8 Bh[2], Bl[2];
#pragma unroll
        for (int nt = 0; nt < 2; ++nt) {
          const int t = nt * 16 + lrow;
          Bh[nt] = *reinterpret_cast<const bf16x8*>(cbh + t * 320 + c0);
          Bl[nt] = *reinterpret_cast<const bf16x8*>(cbl + t * 320 + c0);
        }
        if (kp < 4) {
          const int c1 = c0 + 32;
#pragma unroll
          for (int mt = 0; mt < 3; ++mt) {
            const ushort* rp = rp0 + mt * 16 * 640;
            AhA[mt] = *reinterpret_cast<const bf16x8*>(rp + c1);
            AlA[mt] = *reinterpret_cast<const bf16x8*>(rp + c1 + 320);
          }
        }
#pragma unroll
        for (int mt = 0; mt < 3; ++mt)
#pragma unroll
          for (int nt = 0; nt < 2; ++nt) {
            acc[mt][nt] = MFMA16(AhB[mt], Bh[nt], acc[mt][nt]);
            acc[mt][nt] = MFMA16(AhB[mt], Bl[nt], acc[mt][nt]);
            acc[mt][nt] = MFMA16(AlB[mt], Bh[nt], acc[mt][nt]);
          }
      }
    }
#pragma unroll
    for (int mt = 0; mt < 3; ++mt)
#pragma unroll
      for (int nt = 0; nt < 2; ++nt)
#pragma unroll
        for (int r = 0; r < 4; ++r) {
          const int o = w * 48 + mt * 16 + kg * 4 + r;
          qk_s[o * 36 + nt * 16 + lrow] = acc[mt][nt][r] + bal[o];
        }
  }
  __syncthreads();

  // ---- P2: scores + softmax; o runs to 80 (pad rows are exact zeros); dual acc chains
  {
    const int sg = tid & 7, tq = tid >> 3;
    const int s0 = sg * 4;
    float scA[4] = {0.f, 0.f, 0.f, 0.f}, scB[4] = {0.f, 0.f, 0.f, 0.f};
#pragma unroll 8
    for (int o = 0; o < 80; o += 2) {
      const float qa = qk_s[o * 36 + tq];
      const float4 ka = *reinterpret_cast<const float4*>(&qk_s[(96 + o) * 36 + s0]);
      const float qb = qk_s[(o + 1) * 36 + tq];
      const float4 kb = *reinterpret_cast<const float4*>(&qk_s[(97 + o) * 36 + s0]);
      scA[0] = fmaf(qa, ka.x, scA[0]); scB[0] = fmaf(qb, kb.x, scB[0]);
      scA[1] = fmaf(qa, ka.y, scA[1]); scB[1] = fmaf(qb, kb.y, scB[1]);
      scA[2] = fmaf(qa, ka.z, scA[2]); scB[2] = fmaf(qb, kb.z, scB[2]);
      scA[3] = fmaf(qa, ka.w, scA[3]); scB[3] = fmaf(qb, kb.w, scB[3]);
    }
    float sc[4];
#pragma unroll
    for (int u = 0; u < 4; ++u) sc[u] = scA[u] + scB[u];
    float m = fmaxf(fmaxf(sc[0], sc[1]), fmaxf(sc[2], sc[3]));
    m = fmaxf(m, __shfl_xor(m, 1));
    m = fmaxf(m, __shfl_xor(m, 2));
    m = fmaxf(m, __shfl_xor(m, 4));
    float e[4], ssum = 0.f;
#pragma unroll
    for (int u = 0; u < 4; ++u) { e[u] = expf(sc[u] - m); ssum += e[u]; }
    ssum += __shfl_xor(ssum, 1);
    ssum += __shfl_xor(ssum, 2);
    ssum += __shfl_xor(ssum, 4);
    const float inv = 1.0f / ssum;
#pragma unroll
    for (int u = 0; u < 4; ++u) at_s[tq * 36 + s0 + u] = e[u] * inv;
  }
  __syncthreads();

  // ---- P3: v rows [192,512) in 2 chunks {192,128}; 1-pass bf16, 2-deep A-prefetch
#pragma unroll
  for (int ch = 0; ch < 2; ++ch) {
    const int RB = 192 + ch * 192;
    const int nmt = ch ? 2 : 3;
    f32x4 vacc[3][2];
#pragma unroll
    for (int a = 0; a < 3; ++a)
#pragma unroll
      for (int b2 = 0; b2 < 2; ++b2) vacc[a][b2] = (f32x4){0.f, 0.f, 0.f, 0.f};
    const ushort* vp0 = kbi + (size_t)(RB + w * 16 + lrow) * 640;
    bf16x8 AvA[3], AvB[3];
    {  // preload kstep 0
      const int c0 = kg * 8;
      for (int mi = 0; mi < nmt; ++mi)
        AvA[mi] = *reinterpret_cast<const bf16x8*>(vp0 + mi * 64 * 640 + c0);
    }
#pragma unroll
    for (int kp = 0; kp < 5; ++kp) {
      {  // even
        const int c0 = (2 * kp) * 32 + kg * 8;
        bf16x8 Bh[2];
#pragma unroll
        for (int nt = 0; nt < 2; ++nt)
          Bh[nt] = *reinterpret_cast<const bf16x8*>(cbh + (nt * 16 + lrow) * 320 + c0);
        const int c1 = c0 + 32;
        for (int mi = 0; mi < nmt; ++mi)
          AvB[mi] = *reinterpret_cast<const bf16x8*>(vp0 + mi * 64 * 640 + c1);
        for (int mi = 0; mi < nmt; ++mi)
#pragma unroll
          for (int nt = 0; nt < 2; ++nt)
            vacc[mi][nt] = MFMA16(AvA[mi], Bh[nt], vacc[mi][nt]);
      }
      {  // odd
        const int c0 = (2 * kp + 1) * 32 + kg * 8;
        bf16x8 Bh[2];
#pragma unroll
        for (int nt = 0; nt < 2; ++nt)
          Bh[nt] = *reinterpret_cast<const bf16x8*>(cbh + (nt * 16 + lrow) * 320 + c0);
        if (kp < 4) {
          const int c1 = c0 + 32;
          for (int mi = 0; mi < nmt; ++mi)
            AvA[mi] = *reinterpret_cast<const bf16x8*>(vp0 + mi * 64 * 640 + c1);
        }
        for (int mi = 0; mi < nmt; ++mi)
#pragma unroll
          for (int nt = 0; nt < 2; ++nt)
            vacc[mi][nt] = MFMA16(AvB[mi], Bh[nt], vacc[mi][nt]);
      }
    }
    if (ch) __syncthreads();   // prior 3b readers of qk_s done
    for (int mi = 0; mi < nmt; ++mi)
#pragma unroll
      for (int nt = 0; nt < 2; ++nt)
#pragma unroll
        for (int r = 0; r < 4; ++r) {
          const int vl = (w + mi * 4) * 16 + kg * 4 + r;
          qk_s[vl * 36 + nt * 16 + lrow] = vacc[mi][nt][r] + bal[RB + vl];
        }
    __syncthreads();
    // 3b: sa = v @ attn^T, residual, max over t
    {
      const int tl = tid & 15, cc = tid >> 4;
      float a0[32], a1[32];
#pragma unroll
      for (int s2 = 0; s2 < 32; ++s2) {
        a0[s2] = at_s[tl * 36 + s2];
        a1[s2] = at_s[(tl + 16) * 36 + s2];
      }
      const int jn = ch ? 7 : 12;
#pragma unroll 3
      for (int j = 0; j < jn; ++j) {
        const int cl = cc + 16 * j;
        const int cgl = ch * 192 + cl;
        if (cgl < 300) {
          float s0a = 0.f, s0b = 0.f, s1a = 0.f, s1b = 0.f;
#pragma unroll
          for (int sq = 0; sq < 4; ++sq) {
            const float4 v4 = *reinterpret_cast<const float4*>(&qk_s[cl * 36 + sq * 4]);
            const float vv[4] = {v4.x, v4.y, v4.z, v4.w};
#pragma unroll
            for (int u = 0; u < 4; ++u) {
              s0a = fmaf(vv[u], a0[sq * 4 + u], s0a);
              s1a = fmaf(vv[u], a1[sq * 4 + u], s1a);
            }
          }
#pragma unroll
          for (int sq = 4; sq < 8; ++sq) {
            const float4 v4 = *reinterpret_cast<const float4*>(&qk_s[cl * 36 + sq * 4]);
            const float vv[4] = {v4.x, v4.y, v4.z, v4.w};
#pragma unroll
            for (int u = 0; u < 4; ++u) {
              s0b = fmaf(vv[u], a0[sq * 4 + u], s0b);
              s1b = fmaf(vv[u], a1[sq * 4 + u], s1b);
            }
          }
          const float v0 = fmaf(gamma, s0a + s0b, cap[(size_t)n * 9600 + tl * 300 + cgl]);
          const float v1 = fmaf(gamma, s1a + s1b, cap[(size_t)n * 9600 + (tl + 16) * 300 + cgl]);
          float mx = fmaxf(v0, v1);
          mx = fmaxf(mx, __shfl_xor(mx, 1));
          mx = fmaxf(mx, __shfl_xor(mx, 2));
          mx = fmaxf(mx, __shfl_xor(mx, 4));
          mx = fmaxf(mx, __shfl_xor(mx, 8));
          if (tl == 0) x_all[((size_t)i * 64 + n) * 300 + cgl] = mx;
        }
      }
    }
  }
}

// ---------------- K5a: h1 = x @ W1^T + b1 ----------------
__global__ void __launch_bounds__(256, 4) k_h1(
    const float* __restrict__ x_all, const float* __restrict__ W1,
    const float* __restrict__ b1, float* __restrict__ h1) {
  __shared__ float xt[32 * 68];    // [c][n]
  __shared__ float wt[32 * 132];   // [c][e]
  const int ec = blockIdx.x, i = blockIdx.y, tid = threadIdx.x;
  const int e0c = ec * 128;
  const int eg = tid & 15, ng = tid >> 4;
  const int e0 = eg * 8, n0 = ng * 4;
  float acc[4][8] = {};
  for (int cb = 0; cb < 10; ++cb) {
    const int c0 = cb * 32;
    __syncthreads();
    for (int k = 0; k < 8; ++k) {
      const int idx = tid + 256 * k;
      const int nn = idx >> 5, cl = idx & 31;
      const int c = c0 + cl;
      xt[cl * 68 + nn] = (c < 300) ? x_all[((size_t)i * 64 + nn) * 300 + c] : 0.0f;
    }
    for (int k = 0; k < 16; ++k) {
      const int idx = tid + 256 * k;
      const int ee = idx >> 5, cl = idx & 31;
      const int c = c0 + cl;
      wt[cl * 132 + ee] = (c < 300) ? W1[(size_t)(e0c + ee) * 300 + c] : 0.0f;
    }
    __syncthreads();
#pragma unroll 4
    for (int cl = 0; cl < 32; ++cl) {
      const float4 xv = *reinterpret_cast<const float4*>(&xt[cl * 68 + n0]);
      const float4 wa = *reinterpret_cast<const float4*>(&wt[cl * 132 + e0]);
      const float4 wb = *reinterpret_cast<const float4*>(&wt[cl * 132 + e0 + 4]);
      const float xv4[4] = {xv.x, xv.y, xv.z, xv.w};
      const float wv8[8] = {wa.x, wa.y, wa.z, wa.w, wb.x, wb.y, wb.z, wb.w};
#pragma unroll
      for (int u = 0; u < 4; ++u)
#pragma unroll
        for (int v = 0; v < 8; ++v) acc[u][v] = fmaf(xv4[u], wv8[v], acc[u][v]);
    }
  }
  float b1v[8];
#pragma unroll
  for (int v = 0; v < 8; ++v) b1v[v] = b1[e0c + e0 + v];
#pragma unroll
  for (int u = 0; u < 4; ++u) {
    float* dst = h1 + ((size_t)i * 64 + n0 + u) * 512 + e0c + e0;
    *reinterpret_cast<float4*>(dst) =
        make_float4(acc[u][0] + b1v[0], acc[u][1] + b1v[1], acc[u][2] + b1v[2], acc[u][3] + b1v[3]);
    *reinterpret_cast<float4*>(dst + 4) =
        make_float4(acc[u][4] + b1v[4], acc[u][5] + b1v[5], acc[u][6] + b1v[6], acc[u][7] + b1v[7]);
  }
}

// ---------------- K5b: BN1+relu, h2, BN2+relu, out ----------------
__global__ void __launch_bounds__(256) k_mlp(
    const float* __restrict__ h1, const float* __restrict__ bn1s, const float* __restrict__ bn1b,
    const float* __restrict__ W2, const float* __restrict__ b2,
    const float* __restrict__ bn2s, const float* __restrict__ bn2b,
    const float* __restrict__ W3, const float* __restrict__ b3, float* __restrict__ out) {
  __shared__ float h1s[64 * 521];
  __shared__ float h2s[64 * 65];
  const int i = blockIdx.x, tid = threadIdx.x;
  for (int half = 0; half < 2; ++half) {
    const int e = tid + 256 * half;
    float s1 = 0.f, s2 = 0.f;
    for (int nn = 0; nn < 64; ++nn) {
      const float v = h1[((size_t)i * 64 + nn) * 512 + e];
      h1s[nn * 521 + e] = v;
      s1 += v;
      s2 += v * v;
    }
    const float mu = s1 * (1.0f / 64.0f);
    const float var = s2 * (1.0f / 64.0f) - mu * mu;
    const float scale = bn1s[e] / sqrtf(var + EPSB);
    const float shift = bn1b[e] - mu * scale;
    for (int nn = 0; nn < 64; ++nn) {
      const float v = fmaf(h1s[nn * 521 + e], scale, shift);
      h1s[nn * 521 + e] = fmaxf(v, 0.0f);
    }
  }
  __syncthreads();
  {
    const int dg = tid & 15, ng = tid >> 4;
    const int d0 = dg * 4, n0 = ng * 4;
    float acc[4][4] = {};
#pragma unroll 2
    for (int e = 0; e < 512; ++e) {
      float h4[4], w4[4];
#pragma unroll
      for (int u = 0; u < 4; ++u) h4[u] = h1s[(n0 + u) * 521 + e];
#pragma unroll
      for (int v = 0; v < 4; ++v) w4[v] = W2[(size_t)(d0 + v) * 512 + e];
#pragma unroll
      for (int u = 0; u < 4; ++u)
#pragma unroll
        for (int v = 0; v < 4; ++v) acc[u][v] = fmaf(h4[u], w4[v], acc[u][v]);
    }
#pragma unroll
    for (int u = 0; u < 4; ++u)
#pragma unroll
      for (int v = 0; v < 4; ++v) h2s[(n0 + u) * 65 + d0 + v] = acc[u][v] + b2[d0 + v];
  }
  __syncthreads();
  if (tid < 64) {
    const int d = tid;
    float s1 = 0.f, s2 = 0.f;
    for (int nn = 0; nn < 64; ++nn) {
      const float v = h2s[nn * 65 + d];
      s1 += v;
      s2 += v * v;
    }
    const float mu = s1 * (1.0f / 64.0f);
    const float var = s2 * (1.0f / 64.0f) - mu * mu;
    const float scale = bn2s[d] / sqrtf(var + EPSB);
    const float shift = bn2b[d] - mu * scale;
    for (int nn = 0; nn < 64; ++nn)
      h2s[nn * 65 + d] = fmaxf(fmaf(h2s[nn * 65 + d], scale, shift), 0.0f);
  }
  __syncthreads();
  if (tid < 64) {
    const int nn = tid;
    float acc = b3[0];
    for (int d = 0; d < 64; ++d) acc = fmaf(h2s[nn * 65 + d], W3[d], acc);
    out[i * 64 + nn] = acc;
  }
}

extern "C" void kernel_launch(void* const* d_in, const int* in_sizes, int n_in,
                              void* d_out, int out_size, void* d_ws, size_t ws_size,
                              hipStream_t stream) {
  const float* img  = (const float*)d_in[0];
  const float* cap  = (const float*)d_in[1];
  const float* adW  = (const float*)d_in[2];
  const float* adb  = (const float*)d_in[3];
  const float* qkW  = (const float*)d_in[4];
  const float* qkb  = (const float*)d_in[5];
  const float* qbW  = (const float*)d_in[6];
  const float* qbb  = (const float*)d_in[7];
  const float* qbns = (const float*)d_in[8];
  const float* qbnb = (const float*)d_in[9];
  const float* kkW  = (const float*)d_in[10];
  const float* kkb  = (const float*)d_in[11];
  const float* kbW  = (const float*)d_in[12];
  const float* kbb  = (const float*)d_in[13];
  const float* kbns = (const float*)d_in[14];
  const float* kbnb = (const float*)d_in[15];
  const float* vkW  = (const float*)d_in[16];
  const float* vkb  = (const float*)d_in[17];
  const float* vbW  = (const float*)d_in[18];
  const float* vbb  = (const float*)d_in[19];
  const float* vbns = (const float*)d_in[20];
  const float* vbnb = (const float*)d_in[21];
  const float* gamma= (const float*)d_in[22];
  const float* W1   = (const float*)d_in[23];
  const float* b1   = (const float*)d_in[24];
  const float* bn1s = (const float*)d_in[25];
  const float* bn1b = (const float*)d_in[26];
  const float* W2   = (const float*)d_in[27];
  const float* b2   = (const float*)d_in[28];
  const float* bn2s = (const float*)d_in[29];
  const float* bn2b = (const float*)d_in[30];
  const float* W3   = (const float*)d_in[31];
  const float* b3   = (const float*)d_in[32];

  float* ws    = (float*)d_ws;
  float* base  = ws + OFS_BASE;
  float* ball  = ws + OFS_BALL;
  float* mean  = ws + OFS_MEAN;
  ushort* capB = (ushort*)(ws + OFS_CAPB);
  float* rawP  = ws + OFS_RAWP;
  ushort* kall = (ushort*)(ws + OFS_RAWP);
  float* x_all = ws + OFS_X;
  float* h1    = ws + OFS_H1;    // aliases rawP/kall (dead after k_attn4)
  float* out   = (float*)d_out;

  k_mean<<<512, 256, 0, stream>>>(img, mean);
  k_base<<<128, 128, 0, stream>>>(mean, adW, adb, base);
  k_hyper<<<352, 256, 0, stream>>>(qkW, qkb, base, rawP, 22500, 0);
  k_hyper<<<352, 256, 0, stream>>>(kkW, kkb, base, rawP, 22500, 96);
  k_hyper<<<1407, 256, 0, stream>>>(vkW, vkb, base, rawP, 90000, 192);
  k_bias<<<dim3(2, 128), 256, 0, stream>>>(qbW, qbb, kbW, kbb, vbW, vbb, base, ball);
  k_capb<<<2560, 256, 0, stream>>>(cap, capB);
  k_bnt2<<<16384, 256, 0, stream>>>(rawP, qbns, qbnb, kbns, kbnb, vbns, vbnb);
  k_attn4<<<dim3(64, 128), 256, 0, stream>>>(cap, kall, capB, ball, gamma, x_all);
  k_h1<<<dim3(4, 128), 256, 0, stream>>>(x_all, W1, b1, h1);
  k_mlp<<<128, 256, 0, stream>>>(h1, bn1s, bn1b, W2, b2, bn2s, bn2b, W3, b3, out);
}

// Round 5
// 738.854 us; speedup vs baseline: 4.3141x; 1.4839x over previous
//
#include <hip/hip_runtime.h>
#include <math.h>

#define EPSB 1e-5f

// Bi=128 Bc=64 T=32 C=300 OQK=75 H=128 LAT=1024
// Padded stacked o-dim (512): q [0,96) (75 real), k [96,192) (75 real), v [192,512) (300 real)
// c padded 300 -> 320.
// Packed MFMA operand layout (per image): [ot=32][ks=10][plane=2][lane=64][8] ushort
//   element (o=16*ot+lr, c=32*ks+8*kg+e), lane=kg*16+lr  -> every fragment load = 1KB contiguous/wave
// ws layout (float offsets):
static const long OFS_BASE  = 0;                      // 128*128
static const long OFS_BALL  = 16384;                  // 128*512
static const long OFS_MEAN  = 81920;                  // 128*1024
static const long OFS_CAPB  = 212992;                 // capP: 64*2*10*2*512 ushort = 655360 floats
static const long OFS_RAWP  = 868352;                 // 128*512*320 fp32 -> packed bf16 hi|lo in place
static const long OFS_X     = 21839872;               // 128*64*300
static const long OFS_H1    = OFS_RAWP;               // alias (kall dead after k_attn5)

using bf16x8 = __attribute__((ext_vector_type(8))) __bf16;
using f32x4  = __attribute__((ext_vector_type(4))) float;
#define MFMA16(a, b, c) __builtin_amdgcn_mfma_f32_16x16x32_bf16(a, b, c, 0, 0, 0)

__device__ inline ushort f2bf(float f) {
  const unsigned u = __float_as_uint(f);
  return (ushort)((u + 0x7FFFu + ((u >> 16) & 1u)) >> 16);
}
__device__ inline float bf2f(ushort h) { return __uint_as_float(((unsigned)h) << 16); }

// ---------------- K1a: img_mean over 36 regions ----------------
__global__ void k_mean(const float* __restrict__ img, float* __restrict__ mean) {
  const int idx = blockIdx.x * 256 + threadIdx.x;      // 131072 total
  const int i = idx >> 10, l = idx & 1023;
  const float* p = img + (size_t)i * 36 * 1024 + l;
  float s = 0.f;
#pragma unroll
  for (int r = 0; r < 36; ++r) s += p[r * 1024];
  mean[idx] = s * (1.0f / 36.0f);
}

// ---------------- K1b: base = mean @ adapt_W^T + adapt_b ----------------
__global__ void k_base(const float* __restrict__ mean, const float* __restrict__ W,
                       const float* __restrict__ b, float* __restrict__ base) {
  __shared__ float m_s[1024];
  const int i = blockIdx.x, tid = threadIdx.x;   // 128 threads
  for (int k = 0; k < 8; ++k) m_s[tid + 128 * k] = mean[i * 1024 + tid + 128 * k];
  __syncthreads();
  float acc = b[tid];
  const float* wr = W + (size_t)tid * 1024;
#pragma unroll 4
  for (int l = 0; l < 1024; ++l) acc = fmaf(m_s[l], wr[l], acc);
  base[i * 128 + tid] = acc;
}

// ---------------- K2: hypernet GEMM into padded rawP [i][512][320] ----------------
__global__ void __launch_bounds__(256, 4) k_hyper(
    const float* __restrict__ W, const float* __restrict__ bvec,
    const float* __restrict__ base, float* __restrict__ rawP, const int J, const int R0) {
  __shared__ float bt[128 * 132];          // base transposed [h][i]
  const int tid = threadIdx.x;
  for (int k = 0; k < 64; ++k) {
    const int idx = tid + 256 * k;         // 16384 = 128i x 128h
    bt[(idx & 127) * 132 + (idx >> 7)] = base[idx];
  }
  __syncthreads();
  const int j0 = blockIdx.x * 64;
  const int ig = tid & 15, jg = tid >> 4;
  const int i0 = ig * 8;
  int jj[4];
#pragma unroll
  for (int r = 0; r < 4; ++r) jj[r] = min(j0 + jg * 4 + r, J - 1);
  const float* w0 = W + (size_t)jj[0] * 128;
  const float* w1 = W + (size_t)jj[1] * 128;
  const float* w2 = W + (size_t)jj[2] * 128;
  const float* w3 = W + (size_t)jj[3] * 128;
  float acc[4][8] = {};
#pragma unroll 4
  for (int h = 0; h < 128; ++h) {
    const float4 bA = *reinterpret_cast<const float4*>(&bt[h * 132 + i0]);
    const float4 bB = *reinterpret_cast<const float4*>(&bt[h * 132 + i0 + 4]);
    const float bv[8] = {bA.x, bA.y, bA.z, bA.w, bB.x, bB.y, bB.z, bB.w};
    const float wv[4] = {w0[h], w1[h], w2[h], w3[h]};
#pragma unroll
    for (int r = 0; r < 4; ++r)
#pragma unroll
      for (int u = 0; u < 8; ++u) acc[r][u] = fmaf(wv[r], bv[u], acc[r][u]);
  }
  const float bb[4] = {bvec[jj[0]], bvec[jj[1]], bvec[jj[2]], bvec[jj[3]]};
  const int jbase = j0 + jg * 4;
  if (jbase + 3 < J) {
    const int o = jbase / 300, c = jbase - o * 300;
    if (c <= 296) {   // all 4 in one row; aligned float4
#pragma unroll
      for (int u = 0; u < 8; ++u) {
        float* rp = rawP + ((size_t)(i0 + u) * 512 + R0) * 320;
        *reinterpret_cast<float4*>(rp + o * 320 + c) =
            make_float4(acc[0][u] + bb[0], acc[1][u] + bb[1], acc[2][u] + bb[2], acc[3][u] + bb[3]);
      }
    } else {
#pragma unroll
      for (int u = 0; u < 8; ++u) {
        float* rp = rawP + ((size_t)(i0 + u) * 512 + R0) * 320;
#pragma unroll
        for (int r = 0; r < 4; ++r) {
          const int jr = jbase + r;
          const int o2 = jr / 300, c2 = jr - o2 * 300;
          rp[o2 * 320 + c2] = acc[r][u] + bb[r];
        }
      }
    }
  } else {
#pragma unroll
    for (int u = 0; u < 8; ++u) {
      float* rp = rawP + ((size_t)(i0 + u) * 512 + R0) * 320;
#pragma unroll
      for (int r = 0; r < 4; ++r) {
        const int jr = jbase + r;
        if (jr < J) {
          const int o2 = jr / 300, c2 = jr - o2 * 300;
          rp[o2 * 320 + c2] = acc[r][u] + bb[r];
        }
      }
    }
  }
}

// ---------------- K2b: stacked conv biases ball[i][512] ----------------
__global__ void k_bias(const float* __restrict__ qbW, const float* __restrict__ qbb,
                       const float* __restrict__ kbW, const float* __restrict__ kbb,
                       const float* __restrict__ vbW, const float* __restrict__ vbb,
                       const float* __restrict__ base, float* __restrict__ ball) {
  __shared__ float bs[128];
  const int i = blockIdx.y, tid = threadIdx.x;
  if (tid < 128) bs[tid] = base[i * 128 + tid];
  __syncthreads();
  const int o = blockIdx.x * 256 + tid;
  if (o >= 512) return;
  const float* Wr = nullptr;
  float bb = 0.0f;
  if (o < 75)                   { Wr = qbW + (size_t)o * 128;         bb = qbb[o]; }
  else if (o >= 96 && o < 171)  { Wr = kbW + (size_t)(o - 96) * 128;  bb = kbb[o - 96]; }
  else if (o >= 192 && o < 492) { Wr = vbW + (size_t)(o - 192) * 128; bb = vbb[o - 192]; }
  float acc = 0.0f;
  if (Wr) {
#pragma unroll 4
    for (int h = 0; h < 128; ++h) acc = fmaf(Wr[h], bs[h], acc);
    acc += bb;
  }
  ball[i * 512 + o] = acc;
}

// ---------------- K2c: cap -> packed split-bf16 capP [n][nt=2][ks=10][pl=2][64][8] ----------------
__global__ void __launch_bounds__(256) k_capp(const float* __restrict__ cap,
                                              ushort* __restrict__ capP) {
  __shared__ float ct[32 * 301];
  const int n = blockIdx.x, tid = threadIdx.x;
  const float* capn = cap + (size_t)n * 9600;
  {  // load 32x300 row-major -> LDS [t][c] (pad 301)
    const int r = tid >> 3, c8 = tid & 7;
    for (int m = 0; m < 38; ++m) {
      const int c = c8 + 8 * m;
      if (c < 300) ct[r * 301 + c] = capn[r * 300 + c];
    }
  }
  __syncthreads();
  ushort* dst = capP + (size_t)n * 20480;
  for (int u = 0; u < 10; ++u) {
    const int ul = tid + 256 * u;         // 2560 lane-units of 16B
    const int unit = ul >> 6, lane = ul & 63;
    const int nt = unit / 20, rem = unit % 20;
    const int ks = rem >> 1, pl = rem & 1;
    const int kg = lane >> 4, lr = lane & 15;
    const int t = nt * 16 + lr;
    ushort o8[8];
#pragma unroll
    for (int e = 0; e < 8; ++e) {
      const int c = 32 * ks + 8 * kg + e;
      const float val = (c < 300) ? ct[t * 301 + c] : 0.f;
      const ushort hi = f2bf(val);
      o8[e] = pl ? f2bf(val - bf2f(hi)) : hi;
    }
    uint4 pk;
    pk.x = (uint)o8[0] | ((uint)o8[1] << 16);
    pk.y = (uint)o8[2] | ((uint)o8[3] << 16);
    pk.z = (uint)o8[4] | ((uint)o8[5] << 16);
    pk.w = (uint)o8[6] | ((uint)o8[7] << 16);
    *reinterpret_cast<uint4*>(dst + unit * 512 + lane * 8) = pk;
  }
}

// ---------------- K3: row-BN + in-place repack fp32 chunk -> packed bf16 hi|lo ----------------
// Block (ot, i) owns chunk rawP + ((i*512 + 16*ot)*320): 16 rows x 1280B == packed 20,480B. No races.
__global__ void __launch_bounds__(256) k_bnt3(float* __restrict__ rawP,
    const float* __restrict__ qs, const float* __restrict__ qb,
    const float* __restrict__ ks_, const float* __restrict__ kb_,
    const float* __restrict__ vs, const float* __restrict__ vb) {
  __shared__ float v_s[16 * 321];
  __shared__ float scl_s[16], shf_s[16];
  const int ot = blockIdx.x, i = blockIdx.y, tid = threadIdx.x;
  float* chunk = rawP + ((size_t)i * 512 + ot * 16) * 320;
  const int rg = tid >> 4, part = tid & 15;
  {  // group rg loads row rg (320 floats incl pad)
    for (int m = 0; m < 20; ++m)
      v_s[rg * 321 + part + 16 * m] = chunk[rg * 320 + part + 16 * m];
  }
  __syncthreads();
  {  // BN stats per row
    const int o = ot * 16 + rg;
    float s = 0.f, b = 0.f;
    bool real = false;
    if (o < 75)                    { s = qs[o];       b = qb[o];       real = true; }
    else if (o >= 96 && o < 171)   { s = ks_[o - 96]; b = kb_[o - 96]; real = true; }
    else if (o >= 192 && o < 492)  { s = vs[o - 192]; b = vb[o - 192]; real = true; }
    float s1 = 0.f, s2 = 0.f;
    for (int m = 0; m < 19; ++m) {
      const int c = part + 16 * m;
      if (c < 300) {
        const float x = v_s[rg * 321 + c];
        s1 += x;
        s2 += x * x;
      }
    }
    for (int m = 1; m < 16; m <<= 1) { s1 += __shfl_xor(s1, m); s2 += __shfl_xor(s2, m); }
    const float mu = s1 * (1.0f / 300.0f);
    const float var = s2 * (1.0f / 300.0f) - mu * mu;
    const float scale = s / sqrtf(var + EPSB);
    const float shift = b - mu * scale;
    if (part == 0) { scl_s[rg] = real ? scale : 0.f; shf_s[rg] = real ? shift : 0.f; }
  }
  __syncthreads();
  ushort* uch = reinterpret_cast<ushort*>(chunk);
  for (int u = 0; u < 5; ++u) {
    const int ul = tid + 256 * u;         // 1280 lane-units of 16B
    const int unit = ul >> 6, lane = ul & 63;
    const int ks2 = unit >> 1, pl = unit & 1;
    const int kg = lane >> 4, lr = lane & 15;
    const float sc = scl_s[lr], sh = shf_s[lr];
    ushort o8[8];
#pragma unroll
    for (int e = 0; e < 8; ++e) {
      const int c = 32 * ks2 + 8 * kg + e;
      const float val = (c < 300) ? fmaf(v_s[lr * 321 + c], sc, sh) : 0.f;
      const ushort hi = f2bf(val);
      o8[e] = pl ? f2bf(val - bf2f(hi)) : hi;
    }
    uint4 pk;
    pk.x = (uint)o8[0] | ((uint)o8[1] << 16);
    pk.y = (uint)o8[2] | ((uint)o8[3] << 16);
    pk.z = (uint)o8[4] | ((uint)o8[5] << 16);
    pk.w = (uint)o8[6] | ((uint)o8[7] << 16);
    *reinterpret_cast<uint4*>(uch + unit * 512 + lane * 8) = pk;
  }
}

// ---------------- K4: fused attention; packed coalesced operand loads ----------------
// q/k: 3-pass split-bf16 (score precision). v: 1-pass bf16.
__global__ void __launch_bounds__(256, 4) k_attn5(
    const float* __restrict__ cap, const ushort* __restrict__ kall,
    const ushort* __restrict__ capP, const float* __restrict__ ball,
    const float* __restrict__ gptr, float* __restrict__ x_all) {
  __shared__ float qk_s[192 * 36];   // q rows 0-95, k rows 96-191; reused as v chunk buffer
  __shared__ float at_s[32 * 36];
  const int n = blockIdx.x, i = blockIdx.y, tid = threadIdx.x;
  const int lane = tid & 63, w = tid >> 6;
  const int lrow = lane & 15, kg = lane >> 4;
  const float gamma = gptr[0];
  // packed bases, pre-offset by lane
  const ushort* kpL = kall + (size_t)i * 327680 + lane * 8;   // [ot][ks][pl][64][8]
  const ushort* cpL = capP + (size_t)n * 20480 + lane * 8;    // [nt][ks][pl][64][8]
  const float* bal = ball + i * 512;

  // ---- P1: q+k rows [0,192), wave w owns tiles {3w,3w+1,3w+2}; 2-deep A-prefetch
  {
    f32x4 acc[3][2];
#pragma unroll
    for (int a = 0; a < 3; ++a)
#pragma unroll
      for (int b2 = 0; b2 < 2; ++b2) acc[a][b2] = (f32x4){0.f, 0.f, 0.f, 0.f};
    bf16x8 AhA[3], AlA[3], AhB[3], AlB[3];
#pragma unroll
    for (int mt = 0; mt < 3; ++mt) {   // preload kstep 0
      const ushort* p = kpL + (size_t)((w * 3 + mt) * 20) * 512;
      AhA[mt] = *reinterpret_cast<const bf16x8*>(p);
      AlA[mt] = *reinterpret_cast<const bf16x8*>(p + 512);
    }
#pragma unroll
    for (int kp = 0; kp < 5; ++kp) {
      {  // even kstep 2kp: consume set A; prefetch 2kp+1 into B
        const int ks = 2 * kp;
        bf16x8 Bh[2], Bl[2];
#pragma unroll
        for (int nt = 0; nt < 2; ++nt) {
          const ushort* p = cpL + (size_t)(nt * 20 + ks * 2) * 512;
          Bh[nt] = *reinterpret_cast<const bf16x8*>(p);
          Bl[nt] = *reinterpret_cast<const bf16x8*>(p + 512);
        }
#pragma unroll
        for (int mt = 0; mt < 3; ++mt) {
          const ushort* p = kpL + (size_t)((w * 3 + mt) * 20 + (ks + 1) * 2) * 512;
          AhB[mt] = *reinterpret_cast<const bf16x8*>(p);
          AlB[mt] = *reinterpret_cast<const bf16x8*>(p + 512);
        }
#pragma unroll
        for (int mt = 0; mt < 3; ++mt)
#pragma unroll
          for (int nt = 0; nt < 2; ++nt) {
            acc[mt][nt] = MFMA16(AhA[mt], Bh[nt], acc[mt][nt]);
            acc[mt][nt] = MFMA16(AhA[mt], Bl[nt], acc[mt][nt]);
            acc[mt][nt] = MFMA16(AlA[mt], Bh[nt], acc[mt][nt]);
          }
      }
      {  // odd kstep 2kp+1: consume set B; prefetch 2kp+2 into A
        const int ks = 2 * kp + 1;
        bf16x8 Bh[2], Bl[2];
#pragma unroll
        for (int nt = 0; nt < 2; ++nt) {
          const ushort* p = cpL + (size_t)(nt * 20 + ks * 2) * 512;
          Bh[nt] = *reinterpret_cast<const bf16x8*>(p);
          Bl[nt] = *reinterpret_cast<const bf16x8*>(p + 512);
        }
        if (kp < 4) {
#pragma unroll
          for (int mt = 0; mt < 3; ++mt) {
            const ushort* p = kpL + (size_t)((w * 3 + mt) * 20 + (ks + 1) * 2) * 512;
            AhA[mt] = *reinterpret_cast<const bf16x8*>(p);
            AlA[mt] = *reinterpret_cast<const bf16x8*>(p + 512);
          }
        }
#pragma unroll
        for (int mt = 0; mt < 3; ++mt)
#pragma unroll
          for (int nt = 0; nt < 2; ++nt) {
            acc[mt][nt] = MFMA16(AhB[mt], Bh[nt], acc[mt][nt]);
            acc[mt][nt] = MFMA16(AhB[mt], Bl[nt], acc[mt][nt]);
            acc[mt][nt] = MFMA16(AlB[mt], Bh[nt], acc[mt][nt]);
          }
      }
    }
#pragma unroll
    for (int mt = 0; mt < 3; ++mt)
#pragma unroll
      for (int nt = 0; nt < 2; ++nt)
#pragma unroll
        for (int r = 0; r < 4; ++r) {
          const int o = w * 48 + mt * 16 + kg * 4 + r;
          qk_s[o * 36 + nt * 16 + lrow] = acc[mt][nt][r] + bal[o];
        }
  }
  __syncthreads();

  // ---- P2: scores + softmax; o runs to 80 (pad rows exact zeros); dual acc chains
  {
    const int sg = tid & 7, tq = tid >> 3;
    const int s0 = sg * 4;
    float scA[4] = {0.f, 0.f, 0.f, 0.f}, scB[4] = {0.f, 0.f, 0.f, 0.f};
#pragma unroll 8
    for (int o = 0; o < 80; o += 2) {
      const float qa = qk_s[o * 36 + tq];
      const float4 ka = *reinterpret_cast<const float4*>(&qk_s[(96 + o) * 36 + s0]);
      const float qb = qk_s[(o + 1) * 36 + tq];
      const float4 kb = *reinterpret_cast<const float4*>(&qk_s[(97 + o) * 36 + s0]);
      scA[0] = fmaf(qa, ka.x, scA[0]); scB[0] = fmaf(qb, kb.x, scB[0]);
      scA[1] = fmaf(qa, ka.y, scA[1]); scB[1] = fmaf(qb, kb.y, scB[1]);
      scA[2] = fmaf(qa, ka.z, scA[2]); scB[2] = fmaf(qb, kb.z, scB[2]);
      scA[3] = fmaf(qa, ka.w, scA[3]); scB[3] = fmaf(qb, kb.w, scB[3]);
    }
    float sc[4];
#pragma unroll
    for (int u = 0; u < 4; ++u) sc[u] = scA[u] + scB[u];
    float m = fmaxf(fmaxf(sc[0], sc[1]), fmaxf(sc[2], sc[3]));
    m = fmaxf(m, __shfl_xor(m, 1));
    m = fmaxf(m, __shfl_xor(m, 2));
    m = fmaxf(m, __shfl_xor(m, 4));
    float e[4], ssum = 0.f;
#pragma unroll
    for (int u = 0; u < 4; ++u) { e[u] = expf(sc[u] - m); ssum += e[u]; }
    ssum += __shfl_xor(ssum, 1);
    ssum += __shfl_xor(ssum, 2);
    ssum += __shfl_xor(ssum, 4);
    const float inv = 1.0f / ssum;
#pragma unroll
    for (int u = 0; u < 4; ++u) at_s[tq * 36 + s0 + u] = e[u] * inv;
  }
  __syncthreads();

  // ---- P3: v tiles [12,32) in 2 chunks {12 tiles, 8 tiles}; 1-pass bf16, 2-deep A-prefetch
#pragma unroll
  for (int ch = 0; ch < 2; ++ch) {
    const int TB = 12 + ch * 12;           // base tile
    const int RB = TB * 16;                // base row
    const int nmt = ch ? 2 : 3;
    f32x4 vacc[3][2];
#pragma unroll
    for (int a = 0; a < 3; ++a)
#pragma unroll
      for (int b2 = 0; b2 < 2; ++b2) vacc[a][b2] = (f32x4){0.f, 0.f, 0.f, 0.f};
    bf16x8 AvA[3], AvB[3];
    for (int mi = 0; mi < nmt; ++mi)       // preload kstep 0 (hi plane only)
      AvA[mi] = *reinterpret_cast<const bf16x8*>(kpL + (size_t)((TB + w + mi * 4) * 20) * 512);
#pragma unroll
    for (int kp = 0; kp < 5; ++kp) {
      {  // even
        const int ks = 2 * kp;
        bf16x8 Bh[2];
#pragma unroll
        for (int nt = 0; nt < 2; ++nt)
          Bh[nt] = *reinterpret_cast<const bf16x8*>(cpL + (size_t)(nt * 20 + ks * 2) * 512);
        for (int mi = 0; mi < nmt; ++mi)
          AvB[mi] = *reinterpret_cast<const bf16x8*>(
              kpL + (size_t)((TB + w + mi * 4) * 20 + (ks + 1) * 2) * 512);
        for (int mi = 0; mi < nmt; ++mi)
#pragma unroll
          for (int nt = 0; nt < 2; ++nt)
            vacc[mi][nt] = MFMA16(AvA[mi], Bh[nt], vacc[mi][nt]);
      }
      {  // odd
        const int ks = 2 * kp + 1;
        bf16x8 Bh[2];
#pragma unroll
        for (int nt = 0; nt < 2; ++nt)
          Bh[nt] = *reinterpret_cast<const bf16x8*>(cpL + (size_t)(nt * 20 + ks * 2) * 512);
        if (kp < 4) {
          for (int mi = 0; mi < nmt; ++mi)
            AvA[mi] = *reinterpret_cast<const bf16x8*>(
                kpL + (size_t)((TB + w + mi * 4) * 20 + (ks + 1) * 2) * 512);
        }
        for (int mi = 0; mi < nmt; ++mi)
#pragma unroll
          for (int nt = 0; nt < 2; ++nt)
            vacc[mi][nt] = MFMA16(AvB[mi], Bh[nt], vacc[mi][nt]);
      }
    }
    if (ch) __syncthreads();   // prior 3b readers of qk_s done
    for (int mi = 0; mi < nmt; ++mi)
#pragma unroll
      for (int nt = 0; nt < 2; ++nt)
#pragma unroll
        for (int r = 0; r < 4; ++r) {
          const int vl = (w + mi * 4) * 16 + kg * 4 + r;
          qk_s[vl * 36 + nt * 16 + lrow] = vacc[mi][nt][r] + bal[RB + vl];
        }
    __syncthreads();
    // 3b: sa = v @ attn^T, residual, max over t
    {
      const int tl = tid & 15, cc = tid >> 4;
      float a0[32], a1[32];
#pragma unroll
      for (int s2 = 0; s2 < 32; ++s2) {
        a0[s2] = at_s[tl * 36 + s2];
        a1[s2] = at_s[(tl + 16) * 36 + s2];
      }
      const int jn = ch ? 7 : 12;
#pragma unroll 3
      for (int j = 0; j < jn; ++j) {
        const int cl = cc + 16 * j;
        const int cgl = ch * 192 + cl;
        if (cgl < 300) {
          float s0a = 0.f, s0b = 0.f, s1a = 0.f, s1b = 0.f;
#pragma unroll
          for (int sq = 0; sq < 4; ++sq) {
            const float4 v4 = *reinterpret_cast<const float4*>(&qk_s[cl * 36 + sq * 4]);
            const float vv[4] = {v4.x, v4.y, v4.z, v4.w};
#pragma unroll
            for (int u = 0; u < 4; ++u) {
              s0a = fmaf(vv[u], a0[sq * 4 + u], s0a);
              s1a = fmaf(vv[u], a1[sq * 4 + u], s1a);
            }
          }
#pragma unroll
          for (int sq = 4; sq < 8; ++sq) {
            const float4 v4 = *reinterpret_cast<const float4*>(&qk_s[cl * 36 + sq * 4]);
            const float vv[4] = {v4.x, v4.y, v4.z, v4.w};
#pragma unroll
            for (int u = 0; u < 4; ++u) {
              s0b = fmaf(vv[u], a0[sq * 4 + u], s0b);
              s1b = fmaf(vv[u], a1[sq * 4 + u], s1b);
            }
          }
          const float v0 = fmaf(gamma, s0a + s0b, cap[(size_t)n * 9600 + tl * 300 + cgl]);
          const float v1 = fmaf(gamma, s1a + s1b, cap[(size_t)n * 9600 + (tl + 16) * 300 + cgl]);
          float mx = fmaxf(v0, v1);
          mx = fmaxf(mx, __shfl_xor(mx, 1));
          mx = fmaxf(mx, __shfl_xor(mx, 2));
          mx = fmaxf(mx, __shfl_xor(mx, 4));
          mx = fmaxf(mx, __shfl_xor(mx, 8));
          if (tl == 0) x_all[((size_t)i * 64 + n) * 300 + cgl] = mx;
        }
      }
    }
  }
}

// ---------------- K5a: h1 = x @ W1^T + b1 ----------------
__global__ void __launch_bounds__(256, 4) k_h1(
    const float* __restrict__ x_all, const float* __restrict__ W1,
    const float* __restrict__ b1, float* __restrict__ h1) {
  __shared__ float xt[32 * 68];    // [c][n]
  __shared__ float wt[32 * 132];   // [c][e]
  const int ec = blockIdx.x, i = blockIdx.y, tid = threadIdx.x;
  const int e0c = ec * 128;
  const int eg = tid & 15, ng = tid >> 4;
  const int e0 = eg * 8, n0 = ng * 4;
  float acc[4][8] = {};
  for (int cb = 0; cb < 10; ++cb) {
    const int c0 = cb * 32;
    __syncthreads();
    for (int k = 0; k < 8; ++k) {
      const int idx = tid + 256 * k;
      const int nn = idx >> 5, cl = idx & 31;
      const int c = c0 + cl;
      xt[cl * 68 + nn] = (c < 300) ? x_all[((size_t)i * 64 + nn) * 300 + c] : 0.0f;
    }
    for (int k = 0; k < 16; ++k) {
      const int idx = tid + 256 * k;
      const int ee = idx >> 5, cl = idx & 31;
      const int c = c0 + cl;
      wt[cl * 132 + ee] = (c < 300) ? W1[(size_t)(e0c + ee) * 300 + c] : 0.0f;
    }
    __syncthreads();
#pragma unroll 4
    for (int cl = 0; cl < 32; ++cl) {
      const float4 xv = *reinterpret_cast<const float4*>(&xt[cl * 68 + n0]);
      const float4 wa = *reinterpret_cast<const float4*>(&wt[cl * 132 + e0]);
      const float4 wb = *reinterpret_cast<const float4*>(&wt[cl * 132 + e0 + 4]);
      const float xv4[4] = {xv.x, xv.y, xv.z, xv.w};
      const float wv8[8] = {wa.x, wa.y, wa.z, wa.w, wb.x, wb.y, wb.z, wb.w};
#pragma unroll
      for (int u = 0; u < 4; ++u)
#pragma unroll
        for (int v = 0; v < 8; ++v) acc[u][v] = fmaf(xv4[u], wv8[v], acc[u][v]);
    }
  }
  float b1v[8];
#pragma unroll
  for (int v = 0; v < 8; ++v) b1v[v] = b1[e0c + e0 + v];
#pragma unroll
  for (int u = 0; u < 4; ++u) {
    float* dst = h1 + ((size_t)i * 64 + n0 + u) * 512 + e0c + e0;
    *reinterpret_cast<float4*>(dst) =
        make_float4(acc[u][0] + b1v[0], acc[u][1] + b1v[1], acc[u][2] + b1v[2], acc[u][3] + b1v[3]);
    *reinterpret_cast<float4*>(dst + 4) =
        make_float4(acc[u][4] + b1v[4], acc[u][5] + b1v[5], acc[u][6] + b1v[6], acc[u][7] + b1v[7]);
  }
}

// ---------------- K5b: BN1+relu, h2, BN2+relu, out ----------------
__global__ void __launch_bounds__(256) k_mlp(
    const float* __restrict__ h1, const float* __restrict__ bn1s, const float* __restrict__ bn1b,
    const float* __restrict__ W2, const float* __restrict__ b2,
    const float* __restrict__ bn2s, const float* __restrict__ bn2b,
    const float* __restrict__ W3, const float* __restrict__ b3, float* __restrict__ out) {
  __shared__ float h1s[64 * 521];
  __shared__ float h2s[64 * 65];
  const int i = blockIdx.x, tid = threadIdx.x;
  for (int half = 0; half < 2; ++half) {
    const int e = tid + 256 * half;
    float s1 = 0.f, s2 = 0.f;
    for (int nn = 0; nn < 64; ++nn) {
      const float v = h1[((size_t)i * 64 + nn) * 512 + e];
      h1s[nn * 521 + e] = v;
      s1 += v;
      s2 += v * v;
    }
    const float mu = s1 * (1.0f / 64.0f);
    const float var = s2 * (1.0f / 64.0f) - mu * mu;
    const float scale = bn1s[e] / sqrtf(var + EPSB);
    const float shift = bn1b[e] - mu * scale;
    for (int nn = 0; nn < 64; ++nn) {
      const float v = fmaf(h1s[nn * 521 + e], scale, shift);
      h1s[nn * 521 + e] = fmaxf(v, 0.0f);
    }
  }
  __syncthreads();
  {
    const int dg = tid & 15, ng = tid >> 4;
    const int d0 = dg * 4, n0 = ng * 4;
    float acc[4][4] = {};
#pragma unroll 2
    for (int e = 0; e < 512; ++e) {
      float h4[4], w4[4];
#pragma unroll
      for (int u = 0; u < 4; ++u) h4[u] = h1s[(n0 + u) * 521 + e];
#pragma unroll
      for (int v = 0; v < 4; ++v) w4[v] = W2[(size_t)(d0 + v) * 512 + e];
#pragma unroll
      for (int u = 0; u < 4; ++u)
#pragma unroll
        for (int v = 0; v < 4; ++v) acc[u][v] = fmaf(h4[u], w4[v], acc[u][v]);
    }
#pragma unroll
    for (int u = 0; u < 4; ++u)
#pragma unroll
      for (int v = 0; v < 4; ++v) h2s[(n0 + u) * 65 + d0 + v] = acc[u][v] + b2[d0 + v];
  }
  __syncthreads();
  if (tid < 64) {
    const int d = tid;
    float s1 = 0.f, s2 = 0.f;
    for (int nn = 0; nn < 64; ++nn) {
      const float v = h2s[nn * 65 + d];
      s1 += v;
      s2 += v * v;
    }
    const float mu = s1 * (1.0f / 64.0f);
    const float var = s2 * (1.0f / 64.0f) - mu * mu;
    const float scale = bn2s[d] / sqrtf(var + EPSB);
    const float shift = bn2b[d] - mu * scale;
    for (int nn = 0; nn < 64; ++nn)
      h2s[nn * 65 + d] = fmaxf(fmaf(h2s[nn * 65 + d], scale, shift), 0.0f);
  }
  __syncthreads();
  if (tid < 64) {
    const int nn = tid;
    float acc = b3[0];
    for (int d = 0; d < 64; ++d) acc = fmaf(h2s[nn * 65 + d], W3[d], acc);
    out[i * 64 + nn] = acc;
  }
}

extern "C" void kernel_launch(void* const* d_in, const int* in_sizes, int n_in,
                              void* d_out, int out_size, void* d_ws, size_t ws_size,
                              hipStream_t stream) {
  const float* img  = (const float*)d_in[0];
  const float* cap  = (const float*)d_in[1];
  const float* adW  = (const float*)d_in[2];
  const float* adb  = (const float*)d_in[3];
  const float* qkW  = (const float*)d_in[4];
  const float* qkb  = (const float*)d_in[5];
  const float* qbW  = (const float*)d_in[6];
  const float* qbb  = (const float*)d_in[7];
  const float* qbns = (const float*)d_in[8];
  const float* qbnb = (const float*)d_in[9];
  const float* kkW  = (const float*)d_in[10];
  const float* kkb  = (const float*)d_in[11];
  const float* kbW  = (const float*)d_in[12];
  const float* kbb  = (const float*)d_in[13];
  const float* kbns = (const float*)d_in[14];
  const float* kbnb = (const float*)d_in[15];
  const float* vkW  = (const float*)d_in[16];
  const float* vkb  = (const float*)d_in[17];
  const float* vbW  = (const float*)d_in[18];
  const float* vbb  = (const float*)d_in[19];
  const float* vbns = (const float*)d_in[20];
  const float* vbnb = (const float*)d_in[21];
  const float* gamma= (const float*)d_in[22];
  const float* W1   = (const float*)d_in[23];
  const float* b1   = (const float*)d_in[24];
  const float* bn1s = (const float*)d_in[25];
  const float* bn1b = (const float*)d_in[26];
  const float* W2   = (const float*)d_in[27];
  const float* b2   = (const float*)d_in[28];
  const float* bn2s = (const float*)d_in[29];
  const float* bn2b = (const float*)d_in[30];
  const float* W3   = (const float*)d_in[31];
  const float* b3   = (const float*)d_in[32];

  float* ws    = (float*)d_ws;
  float* base  = ws + OFS_BASE;
  float* ball  = ws + OFS_BALL;
  float* mean  = ws + OFS_MEAN;
  ushort* capP = (ushort*)(ws + OFS_CAPB);
  float* rawP  = ws + OFS_RAWP;
  ushort* kall = (ushort*)(ws + OFS_RAWP);
  float* x_all = ws + OFS_X;
  float* h1    = ws + OFS_H1;    // aliases rawP/kall (dead after k_attn5)
  float* out   = (float*)d_out;

  k_mean<<<512, 256, 0, stream>>>(img, mean);
  k_base<<<128, 128, 0, stream>>>(mean, adW, adb, base);
  k_hyper<<<352, 256, 0, stream>>>(qkW, qkb, base, rawP, 22500, 0);
  k_hyper<<<352, 256, 0, stream>>>(kkW, kkb, base, rawP, 22500, 96);
  k_hyper<<<1407, 256, 0, stream>>>(vkW, vkb, base, rawP, 90000, 192);
  k_bias<<<dim3(2, 128), 256, 0, stream>>>(qbW, qbb, kbW, kbb, vbW, vbb, base, ball);
  k_capp<<<64, 256, 0, stream>>>(cap, capP);
  k_bnt3<<<dim3(32, 128), 256, 0, stream>>>(rawP, qbns, qbnb, kbns, kbnb, vbns, vbnb);
  k_attn5<<<dim3(64, 128), 256, 0, stream>>>(cap, kall, capP, ball, gamma, x_all);
  k_h1<<<dim3(4, 128), 256, 0, stream>>>(x_all, W1, b1, h1);
  k_mlp<<<128, 256, 0, stream>>>(h1, bn1s, bn1b, W2, b2, bn2s, bn2b, W3, b3, out);
}

// Round 6
// 635.912 us; speedup vs baseline: 5.0125x; 1.1619x over previous
//
#include <hip/hip_runtime.h>
#include <math.h>

#define EPSB 1e-5f

// Bi=128 Bc=64 T=32 C=300 OQK=75 H=128 LAT=1024
// Padded stacked o-dim (512): q [0,96) (75 real), k [96,192) (75 real), v [192,512) (300 real)
// c padded 300 -> 320.
// Packed MFMA operand layout (per image): [ot=32][ks=10][plane=2][lane=64][8] ushort
// ws layout (float offsets):
static const long OFS_BASE  = 0;                      // 128*128
static const long OFS_BALL  = 16384;                  // 128*512
static const long OFS_MEAN  = 81920;                  // 128*1024
static const long OFS_CAPB  = 212992;                 // capP: 64*2*10*2*512 ushort = 655360 floats
static const long OFS_RAWP  = 868352;                 // 128*512*320 fp32 -> packed bf16 hi|lo in place
static const long OFS_X     = 21839872;               // 128*64*300
static const long OFS_H1    = OFS_RAWP;               // alias (kall dead after k_attn6)

using bf16x8 = __attribute__((ext_vector_type(8))) __bf16;
using f32x4  = __attribute__((ext_vector_type(4))) float;
#define MFMA16(a, b, c) __builtin_amdgcn_mfma_f32_16x16x32_bf16(a, b, c, 0, 0, 0)

__device__ inline ushort f2bf(float f) {
  const unsigned u = __float_as_uint(f);
  return (ushort)((u + 0x7FFFu + ((u >> 16) & 1u)) >> 16);
}
__device__ inline float bf2f(ushort h) { return __uint_as_float(((unsigned)h) << 16); }

// ---------------- K1a: img_mean over 36 regions ----------------
__global__ void k_mean(const float* __restrict__ img, float* __restrict__ mean) {
  const int idx = blockIdx.x * 256 + threadIdx.x;      // 131072 total
  const int i = idx >> 10, l = idx & 1023;
  const float* p = img + (size_t)i * 36 * 1024 + l;
  float s = 0.f;
#pragma unroll
  for (int r = 0; r < 36; ++r) s += p[r * 1024];
  mean[idx] = s * (1.0f / 36.0f);
}

// ---------------- K1b: base = mean @ adapt_W^T + adapt_b ----------------
__global__ void k_base(const float* __restrict__ mean, const float* __restrict__ W,
                       const float* __restrict__ b, float* __restrict__ base) {
  __shared__ float m_s[1024];
  const int i = blockIdx.x, tid = threadIdx.x;   // 128 threads
  for (int k = 0; k < 8; ++k) m_s[tid + 128 * k] = mean[i * 1024 + tid + 128 * k];
  __syncthreads();
  float acc = b[tid];
  const float* wr = W + (size_t)tid * 1024;
#pragma unroll 4
  for (int l = 0; l < 1024; ++l) acc = fmaf(m_s[l], wr[l], acc);
  base[i * 128 + tid] = acc;
}

// ---------------- K2: hypernet GEMM into padded rawP [i][512][320] ----------------
__global__ void __launch_bounds__(256, 4) k_hyper(
    const float* __restrict__ W, const float* __restrict__ bvec,
    const float* __restrict__ base, float* __restrict__ rawP, const int J, const int R0) {
  __shared__ float bt[128 * 132];          // base transposed [h][i]
  const int tid = threadIdx.x;
  for (int k = 0; k < 64; ++k) {
    const int idx = tid + 256 * k;         // 16384 = 128i x 128h
    bt[(idx & 127) * 132 + (idx >> 7)] = base[idx];
  }
  __syncthreads();
  const int j0 = blockIdx.x * 64;
  const int ig = tid & 15, jg = tid >> 4;
  const int i0 = ig * 8;
  int jj[4];
#pragma unroll
  for (int r = 0; r < 4; ++r) jj[r] = min(j0 + jg * 4 + r, J - 1);
  const float* w0 = W + (size_t)jj[0] * 128;
  const float* w1 = W + (size_t)jj[1] * 128;
  const float* w2 = W + (size_t)jj[2] * 128;
  const float* w3 = W + (size_t)jj[3] * 128;
  float acc[4][8] = {};
#pragma unroll 4
  for (int h = 0; h < 128; ++h) {
    const float4 bA = *reinterpret_cast<const float4*>(&bt[h * 132 + i0]);
    const float4 bB = *reinterpret_cast<const float4*>(&bt[h * 132 + i0 + 4]);
    const float bv[8] = {bA.x, bA.y, bA.z, bA.w, bB.x, bB.y, bB.z, bB.w};
    const float wv[4] = {w0[h], w1[h], w2[h], w3[h]};
#pragma unroll
    for (int r = 0; r < 4; ++r)
#pragma unroll
      for (int u = 0; u < 8; ++u) acc[r][u] = fmaf(wv[r], bv[u], acc[r][u]);
  }
  const float bb[4] = {bvec[jj[0]], bvec[jj[1]], bvec[jj[2]], bvec[jj[3]]};
  const int jbase = j0 + jg * 4;
  if (jbase + 3 < J) {
    const int o = jbase / 300, c = jbase - o * 300;
    if (c <= 296) {   // all 4 in one row; aligned float4
#pragma unroll
      for (int u = 0; u < 8; ++u) {
        float* rp = rawP + ((size_t)(i0 + u) * 512 + R0) * 320;
        *reinterpret_cast<float4*>(rp + o * 320 + c) =
            make_float4(acc[0][u] + bb[0], acc[1][u] + bb[1], acc[2][u] + bb[2], acc[3][u] + bb[3]);
      }
    } else {
#pragma unroll
      for (int u = 0; u < 8; ++u) {
        float* rp = rawP + ((size_t)(i0 + u) * 512 + R0) * 320;
#pragma unroll
        for (int r = 0; r < 4; ++r) {
          const int jr = jbase + r;
          const int o2 = jr / 300, c2 = jr - o2 * 300;
          rp[o2 * 320 + c2] = acc[r][u] + bb[r];
        }
      }
    }
  } else {
#pragma unroll
    for (int u = 0; u < 8; ++u) {
      float* rp = rawP + ((size_t)(i0 + u) * 512 + R0) * 320;
#pragma unroll
      for (int r = 0; r < 4; ++r) {
        const int jr = jbase + r;
        if (jr < J) {
          const int o2 = jr / 300, c2 = jr - o2 * 300;
          rp[o2 * 320 + c2] = acc[r][u] + bb[r];
        }
      }
    }
  }
}

// ---------------- K2b: stacked conv biases ball[i][512] ----------------
__global__ void k_bias(const float* __restrict__ qbW, const float* __restrict__ qbb,
                       const float* __restrict__ kbW, const float* __restrict__ kbb,
                       const float* __restrict__ vbW, const float* __restrict__ vbb,
                       const float* __restrict__ base, float* __restrict__ ball) {
  __shared__ float bs[128];
  const int i = blockIdx.y, tid = threadIdx.x;
  if (tid < 128) bs[tid] = base[i * 128 + tid];
  __syncthreads();
  const int o = blockIdx.x * 256 + tid;
  if (o >= 512) return;
  const float* Wr = nullptr;
  float bb = 0.0f;
  if (o < 75)                   { Wr = qbW + (size_t)o * 128;         bb = qbb[o]; }
  else if (o >= 96 && o < 171)  { Wr = kbW + (size_t)(o - 96) * 128;  bb = kbb[o - 96]; }
  else if (o >= 192 && o < 492) { Wr = vbW + (size_t)(o - 192) * 128; bb = vbb[o - 192]; }
  float acc = 0.0f;
  if (Wr) {
#pragma unroll 4
    for (int h = 0; h < 128; ++h) acc = fmaf(Wr[h], bs[h], acc);
    acc += bb;
  }
  ball[i * 512 + o] = acc;
}

// ---------------- K2c: cap -> packed split-bf16 capP [n][nt=2][ks=10][pl=2][64][8] ----------------
__global__ void __launch_bounds__(256) k_capp(const float* __restrict__ cap,
                                              ushort* __restrict__ capP) {
  __shared__ float ct[32 * 301];
  const int n = blockIdx.x, tid = threadIdx.x;
  const float* capn = cap + (size_t)n * 9600;
  {  // load 32x300 row-major -> LDS [t][c] (pad 301)
    const int r = tid >> 3, c8 = tid & 7;
    for (int m = 0; m < 38; ++m) {
      const int c = c8 + 8 * m;
      if (c < 300) ct[r * 301 + c] = capn[r * 300 + c];
    }
  }
  __syncthreads();
  ushort* dst = capP + (size_t)n * 20480;
  for (int u = 0; u < 10; ++u) {
    const int ul = tid + 256 * u;         // 2560 lane-units of 16B
    const int unit = ul >> 6, lane = ul & 63;
    const int nt = unit / 20, rem = unit % 20;
    const int ks = rem >> 1, pl = rem & 1;
    const int kg = lane >> 4, lr = lane & 15;
    const int t = nt * 16 + lr;
    ushort o8[8];
#pragma unroll
    for (int e = 0; e < 8; ++e) {
      const int c = 32 * ks + 8 * kg + e;
      const float val = (c < 300) ? ct[t * 301 + c] : 0.f;
      const ushort hi = f2bf(val);
      o8[e] = pl ? f2bf(val - bf2f(hi)) : hi;
    }
    uint4 pk;
    pk.x = (uint)o8[0] | ((uint)o8[1] << 16);
    pk.y = (uint)o8[2] | ((uint)o8[3] << 16);
    pk.z = (uint)o8[4] | ((uint)o8[5] << 16);
    pk.w = (uint)o8[6] | ((uint)o8[7] << 16);
    *reinterpret_cast<uint4*>(dst + unit * 512 + lane * 8) = pk;
  }
}

// ---------------- K3: row-BN + in-place repack fp32 chunk -> packed bf16 hi|lo ----------------
__global__ void __launch_bounds__(256) k_bnt3(float* __restrict__ rawP,
    const float* __restrict__ qs, const float* __restrict__ qb,
    const float* __restrict__ ks_, const float* __restrict__ kb_,
    const float* __restrict__ vs, const float* __restrict__ vb) {
  __shared__ float v_s[16 * 321];
  __shared__ float scl_s[16], shf_s[16];
  const int ot = blockIdx.x, i = blockIdx.y, tid = threadIdx.x;
  float* chunk = rawP + ((size_t)i * 512 + ot * 16) * 320;
  const int rg = tid >> 4, part = tid & 15;
  {
    for (int m = 0; m < 20; ++m)
      v_s[rg * 321 + part + 16 * m] = chunk[rg * 320 + part + 16 * m];
  }
  __syncthreads();
  {
    const int o = ot * 16 + rg;
    float s = 0.f, b = 0.f;
    bool real = false;
    if (o < 75)                    { s = qs[o];       b = qb[o];       real = true; }
    else if (o >= 96 && o < 171)   { s = ks_[o - 96]; b = kb_[o - 96]; real = true; }
    else if (o >= 192 && o < 492)  { s = vs[o - 192]; b = vb[o - 192]; real = true; }
    float s1 = 0.f, s2 = 0.f;
    for (int m = 0; m < 19; ++m) {
      const int c = part + 16 * m;
      if (c < 300) {
        const float x = v_s[rg * 321 + c];
        s1 += x;
        s2 += x * x;
      }
    }
    for (int m = 1; m < 16; m <<= 1) { s1 += __shfl_xor(s1, m); s2 += __shfl_xor(s2, m); }
    const float mu = s1 * (1.0f / 300.0f);
    const float var = s2 * (1.0f / 300.0f) - mu * mu;
    const float scale = s / sqrtf(var + EPSB);
    const float shift = b - mu * scale;
    if (part == 0) { scl_s[rg] = real ? scale : 0.f; shf_s[rg] = real ? shift : 0.f; }
  }
  __syncthreads();
  ushort* uch = reinterpret_cast<ushort*>(chunk);
  for (int u = 0; u < 5; ++u) {
    const int ul = tid + 256 * u;         // 1280 lane-units of 16B
    const int unit = ul >> 6, lane = ul & 63;
    const int ks2 = unit >> 1, pl = unit & 1;
    const int kg = lane >> 4, lr = lane & 15;
    const float sc = scl_s[lr], sh = shf_s[lr];
    ushort o8[8];
#pragma unroll
    for (int e = 0; e < 8; ++e) {
      const int c = 32 * ks2 + 8 * kg + e;
      const float val = (c < 300) ? fmaf(v_s[lr * 321 + c], sc, sh) : 0.f;
      const ushort hi = f2bf(val);
      o8[e] = pl ? f2bf(val - bf2f(hi)) : hi;
    }
    uint4 pk;
    pk.x = (uint)o8[0] | ((uint)o8[1] << 16);
    pk.y = (uint)o8[2] | ((uint)o8[3] << 16);
    pk.z = (uint)o8[4] | ((uint)o8[5] << 16);
    pk.w = (uint)o8[6] | ((uint)o8[7] << 16);
    *reinterpret_cast<uint4*>(uch + unit * 512 + lane * 8) = pk;
  }
}

// ---------------- K4: fused attention; packed loads + MFMA PV ----------------
// q/k: 3-pass split-bf16 (score precision). v: 1-pass bf16. PV: 3-pass split-bf16 MFMA.
__global__ void __launch_bounds__(256, 4) k_attn6(
    const float* __restrict__ cap, const ushort* __restrict__ kall,
    const ushort* __restrict__ capP, const float* __restrict__ ball,
    const float* __restrict__ gptr, float* __restrict__ x_all) {
  __shared__ float qk_s[192 * 36];       // P1/P2: q rows 0-95, k 96-191; P3: packed v tiles
  __shared__ ushort at_p[2 * 2 * 64 * 8]; // packed attn: [tt][pl][lane][8]
  const int n = blockIdx.x, i = blockIdx.y, tid = threadIdx.x;
  const int lane = tid & 63, w = tid >> 6;
  const int lrow = lane & 15, kg = lane >> 4;
  const float gamma = gptr[0];
  const ushort* kpL = kall + (size_t)i * 327680 + lane * 8;   // [ot][ks][pl][64][8]
  const ushort* cpL = capP + (size_t)n * 20480 + lane * 8;    // [nt][ks][pl][64][8]
  const float* bal = ball + i * 512;

  // ---- P1: q+k rows [0,192), wave w owns tiles {3w..3w+2}; 2-deep A-prefetch
  {
    f32x4 acc[3][2];
#pragma unroll
    for (int a = 0; a < 3; ++a)
#pragma unroll
      for (int b2 = 0; b2 < 2; ++b2) acc[a][b2] = (f32x4){0.f, 0.f, 0.f, 0.f};
    bf16x8 AhA[3], AlA[3], AhB[3], AlB[3];
#pragma unroll
    for (int mt = 0; mt < 3; ++mt) {   // preload kstep 0
      const ushort* p = kpL + (size_t)((w * 3 + mt) * 20) * 512;
      AhA[mt] = *reinterpret_cast<const bf16x8*>(p);
      AlA[mt] = *reinterpret_cast<const bf16x8*>(p + 512);
    }
#pragma unroll
    for (int kp = 0; kp < 5; ++kp) {
      {  // even kstep
        const int ks = 2 * kp;
        bf16x8 Bh[2], Bl[2];
#pragma unroll
        for (int nt = 0; nt < 2; ++nt) {
          const ushort* p = cpL + (size_t)(nt * 20 + ks * 2) * 512;
          Bh[nt] = *reinterpret_cast<const bf16x8*>(p);
          Bl[nt] = *reinterpret_cast<const bf16x8*>(p + 512);
        }
#pragma unroll
        for (int mt = 0; mt < 3; ++mt) {
          const ushort* p = kpL + (size_t)((w * 3 + mt) * 20 + (ks + 1) * 2) * 512;
          AhB[mt] = *reinterpret_cast<const bf16x8*>(p);
          AlB[mt] = *reinterpret_cast<const bf16x8*>(p + 512);
        }
#pragma unroll
        for (int mt = 0; mt < 3; ++mt)
#pragma unroll
          for (int nt = 0; nt < 2; ++nt) {
            acc[mt][nt] = MFMA16(AhA[mt], Bh[nt], acc[mt][nt]);
            acc[mt][nt] = MFMA16(AhA[mt], Bl[nt], acc[mt][nt]);
            acc[mt][nt] = MFMA16(AlA[mt], Bh[nt], acc[mt][nt]);
          }
      }
      {  // odd kstep
        const int ks = 2 * kp + 1;
        bf16x8 Bh[2], Bl[2];
#pragma unroll
        for (int nt = 0; nt < 2; ++nt) {
          const ushort* p = cpL + (size_t)(nt * 20 + ks * 2) * 512;
          Bh[nt] = *reinterpret_cast<const bf16x8*>(p);
          Bl[nt] = *reinterpret_cast<const bf16x8*>(p + 512);
        }
        if (kp < 4) {
#pragma unroll
          for (int mt = 0; mt < 3; ++mt) {
            const ushort* p = kpL + (size_t)((w * 3 + mt) * 20 + (ks + 1) * 2) * 512;
            AhA[mt] = *reinterpret_cast<const bf16x8*>(p);
            AlA[mt] = *reinterpret_cast<const bf16x8*>(p + 512);
          }
        }
#pragma unroll
        for (int mt = 0; mt < 3; ++mt)
#pragma unroll
          for (int nt = 0; nt < 2; ++nt) {
            acc[mt][nt] = MFMA16(AhB[mt], Bh[nt], acc[mt][nt]);
            acc[mt][nt] = MFMA16(AhB[mt], Bl[nt], acc[mt][nt]);
            acc[mt][nt] = MFMA16(AlB[mt], Bh[nt], acc[mt][nt]);
          }
      }
    }
#pragma unroll
    for (int mt = 0; mt < 3; ++mt)
#pragma unroll
      for (int nt = 0; nt < 2; ++nt)
#pragma unroll
        for (int r = 0; r < 4; ++r) {
          const int o = w * 48 + mt * 16 + kg * 4 + r;
          qk_s[o * 36 + nt * 16 + lrow] = acc[mt][nt][r] + bal[o];
        }
  }
  __syncthreads();

  // ---- P2: scores + softmax (fp32 VALU); write packed bf16 hi/lo attn in MFMA-B layout
  {
    const int sg = tid & 7, tq = tid >> 3;
    const int s0 = sg * 4;
    float scA[4] = {0.f, 0.f, 0.f, 0.f}, scB[4] = {0.f, 0.f, 0.f, 0.f};
#pragma unroll 8
    for (int o = 0; o < 80; o += 2) {
      const float qa = qk_s[o * 36 + tq];
      const float4 ka = *reinterpret_cast<const float4*>(&qk_s[(96 + o) * 36 + s0]);
      const float qb = qk_s[(o + 1) * 36 + tq];
      const float4 kb = *reinterpret_cast<const float4*>(&qk_s[(97 + o) * 36 + s0]);
      scA[0] = fmaf(qa, ka.x, scA[0]); scB[0] = fmaf(qb, kb.x, scB[0]);
      scA[1] = fmaf(qa, ka.y, scA[1]); scB[1] = fmaf(qb, kb.y, scB[1]);
      scA[2] = fmaf(qa, ka.z, scA[2]); scB[2] = fmaf(qb, kb.z, scB[2]);
      scA[3] = fmaf(qa, ka.w, scA[3]); scB[3] = fmaf(qb, kb.w, scB[3]);
    }
    float sc[4];
#pragma unroll
    for (int u = 0; u < 4; ++u) sc[u] = scA[u] + scB[u];
    float m = fmaxf(fmaxf(sc[0], sc[1]), fmaxf(sc[2], sc[3]));
    m = fmaxf(m, __shfl_xor(m, 1));
    m = fmaxf(m, __shfl_xor(m, 2));
    m = fmaxf(m, __shfl_xor(m, 4));
    float ev[4], ssum = 0.f;
#pragma unroll
    for (int u = 0; u < 4; ++u) { ev[u] = expf(sc[u] - m); ssum += ev[u]; }
    ssum += __shfl_xor(ssum, 1);
    ssum += __shfl_xor(ssum, 2);
    ssum += __shfl_xor(ssum, 4);
    const float inv = 1.0f / ssum;
    // pack: element (t=tq, s=s0+u) -> at_p[((tt*2+pl)*64 + (s>>3)*16 + (t&15))*8 + (s&7)]
    const int tt = tq >> 4, lrp = tq & 15, kgp = sg >> 1, eb = (sg & 1) * 4;
    ushort h4[4], l4[4];
#pragma unroll
    for (int u = 0; u < 4; ++u) {
      const float val = ev[u] * inv;
      const ushort hi = f2bf(val);
      h4[u] = hi;
      l4[u] = f2bf(val - bf2f(hi));
    }
    uint2 ph, pl2;
    ph.x = (uint)h4[0] | ((uint)h4[1] << 16);
    ph.y = (uint)h4[2] | ((uint)h4[3] << 16);
    pl2.x = (uint)l4[0] | ((uint)l4[1] << 16);
    pl2.y = (uint)l4[2] | ((uint)l4[3] << 16);
    *reinterpret_cast<uint2*>(&at_p[((tt * 2 + 0) * 64 + kgp * 16 + lrp) * 8 + eb]) = ph;
    *reinterpret_cast<uint2*>(&at_p[((tt * 2 + 1) * 64 + kgp * 16 + lrp) * 8 + eb]) = pl2;
  }
  __syncthreads();

  // ---- P3: v tiles [12,32) in 2 chunks {12,8 tiles}; 1-pass bf16 proj + MFMA PV
  ushort* vt = reinterpret_cast<ushort*>(qk_s);   // packed v: [tile][pl][64][8]
#pragma unroll
  for (int ch = 0; ch < 2; ++ch) {
    const int TB = 12 + ch * 12;           // base tile in kall
    const int RB = TB * 16;                // base row
    const int nmt = ch ? 2 : 3;
    f32x4 vacc[3][2];
#pragma unroll
    for (int a = 0; a < 3; ++a)
#pragma unroll
      for (int b2 = 0; b2 < 2; ++b2) vacc[a][b2] = (f32x4){0.f, 0.f, 0.f, 0.f};
    bf16x8 AvA[3], AvB[3];
    for (int mi = 0; mi < nmt; ++mi)       // preload kstep 0 (hi plane only)
      AvA[mi] = *reinterpret_cast<const bf16x8*>(kpL + (size_t)((TB + w + mi * 4) * 20) * 512);
#pragma unroll
    for (int kp = 0; kp < 5; ++kp) {
      {  // even
        const int ks = 2 * kp;
        bf16x8 Bh[2];
#pragma unroll
        for (int nt = 0; nt < 2; ++nt)
          Bh[nt] = *reinterpret_cast<const bf16x8*>(cpL + (size_t)(nt * 20 + ks * 2) * 512);
        for (int mi = 0; mi < nmt; ++mi)
          AvB[mi] = *reinterpret_cast<const bf16x8*>(
              kpL + (size_t)((TB + w + mi * 4) * 20 + (ks + 1) * 2) * 512);
        for (int mi = 0; mi < nmt; ++mi)
#pragma unroll
          for (int nt = 0; nt < 2; ++nt)
            vacc[mi][nt] = MFMA16(AvA[mi], Bh[nt], vacc[mi][nt]);
      }
      {  // odd
        const int ks = 2 * kp + 1;
        bf16x8 Bh[2];
#pragma unroll
        for (int nt = 0; nt < 2; ++nt)
          Bh[nt] = *reinterpret_cast<const bf16x8*>(cpL + (size_t)(nt * 20 + ks * 2) * 512);
        if (kp < 4) {
          for (int mi = 0; mi < nmt; ++mi)
            AvA[mi] = *reinterpret_cast<const bf16x8*>(
                kpL + (size_t)((TB + w + mi * 4) * 20 + (ks + 1) * 2) * 512);
        }
        for (int mi = 0; mi < nmt; ++mi)
#pragma unroll
          for (int nt = 0; nt < 2; ++nt)
            vacc[mi][nt] = MFMA16(AvB[mi], Bh[nt], vacc[mi][nt]);
      }
    }
    if (ch) __syncthreads();   // prior P3b readers of vt done
    // store v (bias added) as packed bf16 hi/lo in MFMA-A layout: tile-local
    for (int mi = 0; mi < nmt; ++mi) {
      const int tile = w + mi * 4;
#pragma unroll
      for (int nt = 0; nt < 2; ++nt) {
        const int kgp = nt * 2 + (lrow >> 3), ee = lrow & 7;
#pragma unroll
        for (int r = 0; r < 4; ++r) {
          const int vl = tile * 16 + kg * 4 + r;
          const float val = vacc[mi][nt][r] + bal[RB + vl];
          const ushort hi = f2bf(val);
          vt[((tile * 2 + 0) * 64 + kgp * 16 + kg * 4 + r) * 8 + ee] = hi;
          vt[((tile * 2 + 1) * 64 + kgp * 16 + kg * 4 + r) * 8 + ee] = f2bf(val - bf2f(hi));
        }
      }
    }
    __syncthreads();
    // P3b: MFMA PV: D[c][t] = sum_s v[c][s]*attn[t][s]; 3-pass split
    {
      bf16x8 ah[2], al[2];
#pragma unroll
      for (int tt = 0; tt < 2; ++tt) {
        ah[tt] = *reinterpret_cast<const bf16x8*>(&at_p[((tt * 2 + 0) * 64 + lane) * 8]);
        al[tt] = *reinterpret_cast<const bf16x8*>(&at_p[((tt * 2 + 1) * 64 + lane) * 8]);
      }
      const int npw = ch ? 2 : 3;
      for (int j = 0; j < npw; ++j) {
        const int ct = w * npw + j;
        const int c0 = ch * 192 + ct * 16 + (lane >> 4) * 4;
        const bf16x8 vh  = *reinterpret_cast<const bf16x8*>(&vt[((ct * 2 + 0) * 64 + lane) * 8]);
        const bf16x8 vl8 = *reinterpret_cast<const bf16x8*>(&vt[((ct * 2 + 1) * 64 + lane) * 8]);
        f32x4 a0 = (f32x4){0.f, 0.f, 0.f, 0.f}, a1 = (f32x4){0.f, 0.f, 0.f, 0.f};
        a0 = MFMA16(vh, ah[0], a0);
        a0 = MFMA16(vh, al[0], a0);
        a0 = MFMA16(vl8, ah[0], a0);
        a1 = MFMA16(vh, ah[1], a1);
        a1 = MFMA16(vh, al[1], a1);
        a1 = MFMA16(vl8, ah[1], a1);
        if (c0 < 300) {
          const int t0 = lane & 15;
          const float4 c4a = *reinterpret_cast<const float4*>(&cap[(size_t)n * 9600 + t0 * 300 + c0]);
          const float4 c4b = *reinterpret_cast<const float4*>(&cap[(size_t)n * 9600 + (t0 + 16) * 300 + c0]);
          float mx[4];
          mx[0] = fmaxf(fmaf(gamma, a0[0], c4a.x), fmaf(gamma, a1[0], c4b.x));
          mx[1] = fmaxf(fmaf(gamma, a0[1], c4a.y), fmaf(gamma, a1[1], c4b.y));
          mx[2] = fmaxf(fmaf(gamma, a0[2], c4a.z), fmaf(gamma, a1[2], c4b.z));
          mx[3] = fmaxf(fmaf(gamma, a0[3], c4a.w), fmaf(gamma, a1[3], c4b.w));
#pragma unroll
          for (int mmask = 1; mmask < 16; mmask <<= 1)
#pragma unroll
            for (int r = 0; r < 4; ++r) mx[r] = fmaxf(mx[r], __shfl_xor(mx[r], mmask));
          if ((lane & 15) == 0)
            *reinterpret_cast<float4*>(&x_all[((size_t)i * 64 + n) * 300 + c0]) =
                make_float4(mx[0], mx[1], mx[2], mx[3]);
        }
      }
    }
  }
}

// ---------------- K5a: h1 = x @ W1^T + b1 ----------------
__global__ void __launch_bounds__(256, 4) k_h1(
    const float* __restrict__ x_all, const float* __restrict__ W1,
    const float* __restrict__ b1, float* __restrict__ h1) {
  __shared__ float xt[32 * 68];    // [c][n]
  __shared__ float wt[32 * 132];   // [c][e]
  const int ec = blockIdx.x, i = blockIdx.y, tid = threadIdx.x;
  const int e0c = ec * 128;
  const int eg = tid & 15, ng = tid >> 4;
  const int e0 = eg * 8, n0 = ng * 4;
  float acc[4][8] = {};
  for (int cb = 0; cb < 10; ++cb) {
    const int c0 = cb * 32;
    __syncthreads();
    for (int k = 0; k < 8; ++k) {
      const int idx = tid + 256 * k;
      const int nn = idx >> 5, cl = idx & 31;
      const int c = c0 + cl;
      xt[cl * 68 + nn] = (c < 300) ? x_all[((size_t)i * 64 + nn) * 300 + c] : 0.0f;
    }
    for (int k = 0; k < 16; ++k) {
      const int idx = tid + 256 * k;
      const int ee = idx >> 5, cl = idx & 31;
      const int c = c0 + cl;
      wt[cl * 132 + ee] = (c < 300) ? W1[(size_t)(e0c + ee) * 300 + c] : 0.0f;
    }
    __syncthreads();
#pragma unroll 4
    for (int cl = 0; cl < 32; ++cl) {
      const float4 xv = *reinterpret_cast<const float4*>(&xt[cl * 68 + n0]);
      const float4 wa = *reinterpret_cast<const float4*>(&wt[cl * 132 + e0]);
      const float4 wb = *reinterpret_cast<const float4*>(&wt[cl * 132 + e0 + 4]);
      const float xv4[4] = {xv.x, xv.y, xv.z, xv.w};
      const float wv8[8] = {wa.x, wa.y, wa.z, wa.w, wb.x, wb.y, wb.z, wb.w};
#pragma unroll
      for (int u = 0; u < 4; ++u)
#pragma unroll
        for (int v = 0; v < 8; ++v) acc[u][v] = fmaf(xv4[u], wv8[v], acc[u][v]);
    }
  }
  float b1v[8];
#pragma unroll
  for (int v = 0; v < 8; ++v) b1v[v] = b1[e0c + e0 + v];
#pragma unroll
  for (int u = 0; u < 4; ++u) {
    float* dst = h1 + ((size_t)i * 64 + n0 + u) * 512 + e0c + e0;
    *reinterpret_cast<float4*>(dst) =
        make_float4(acc[u][0] + b1v[0], acc[u][1] + b1v[1], acc[u][2] + b1v[2], acc[u][3] + b1v[3]);
    *reinterpret_cast<float4*>(dst + 4) =
        make_float4(acc[u][4] + b1v[4], acc[u][5] + b1v[5], acc[u][6] + b1v[6], acc[u][7] + b1v[7]);
  }
}

// ---------------- K5b: BN1+relu, h2, BN2+relu, out ----------------
__global__ void __launch_bounds__(256) k_mlp(
    const float* __restrict__ h1, const float* __restrict__ bn1s, const float* __restrict__ bn1b,
    const float* __restrict__ W2, const float* __restrict__ b2,
    const float* __restrict__ bn2s, const float* __restrict__ bn2b,
    const float* __restrict__ W3, const float* __restrict__ b3, float* __restrict__ out) {
  __shared__ float h1s[64 * 521];
  __shared__ float h2s[64 * 65];
  const int i = blockIdx.x, tid = threadIdx.x;
  // coalesced staging of h1 (was stride-2048B scattered)
  for (int m = 0; m < 128; ++m) {
    const int idx = tid + 256 * m;
    h1s[(idx >> 9) * 521 + (idx & 511)] = h1[(size_t)i * 32768 + idx];
  }
  __syncthreads();
  for (int half = 0; half < 2; ++half) {
    const int e = tid + 256 * half;
    float s1 = 0.f, s2 = 0.f;
    for (int nn = 0; nn < 64; ++nn) {
      const float v = h1s[nn * 521 + e];
      s1 += v;
      s2 += v * v;
    }
    const float mu = s1 * (1.0f / 64.0f);
    const float var = s2 * (1.0f / 64.0f) - mu * mu;
    const float scale = bn1s[e] / sqrtf(var + EPSB);
    const float shift = bn1b[e] - mu * scale;
    for (int nn = 0; nn < 64; ++nn) {
      const float v = fmaf(h1s[nn * 521 + e], scale, shift);
      h1s[nn * 521 + e] = fmaxf(v, 0.0f);
    }
  }
  __syncthreads();
  {
    const int dg = tid & 15, ng = tid >> 4;
    const int d0 = dg * 4, n0 = ng * 4;
    float acc[4][4] = {};
#pragma unroll 2
    for (int e = 0; e < 512; ++e) {
      float h4[4], w4[4];
#pragma unroll
      for (int u = 0; u < 4; ++u) h4[u] = h1s[(n0 + u) * 521 + e];
#pragma unroll
      for (int v = 0; v < 4; ++v) w4[v] = W2[(size_t)(d0 + v) * 512 + e];
#pragma unroll
      for (int u = 0; u < 4; ++u)
#pragma unroll
        for (int v = 0; v < 4; ++v) acc[u][v] = fmaf(h4[u], w4[v], acc[u][v]);
    }
#pragma unroll
    for (int u = 0; u < 4; ++u)
#pragma unroll
      for (int v = 0; v < 4; ++v) h2s[(n0 + u) * 65 + d0 + v] = acc[u][v] + b2[d0 + v];
  }
  __syncthreads();
  if (tid < 64) {
    const int d = tid;
    float s1 = 0.f, s2 = 0.f;
    for (int nn = 0; nn < 64; ++nn) {
      const float v = h2s[nn * 65 + d];
      s1 += v;
      s2 += v * v;
    }
    const float mu = s1 * (1.0f / 64.0f);
    const float var = s2 * (1.0f / 64.0f) - mu * mu;
    const float scale = bn2s[d] / sqrtf(var + EPSB);
    const float shift = bn2b[d] - mu * scale;
    for (int nn = 0; nn < 64; ++nn)
      h2s[nn * 65 + d] = fmaxf(fmaf(h2s[nn * 65 + d], scale, shift), 0.0f);
  }
  __syncthreads();
  if (tid < 64) {
    const int nn = tid;
    float acc = b3[0];
    for (int d = 0; d < 64; ++d) acc = fmaf(h2s[nn * 65 + d], W3[d], acc);
    out[i * 64 + nn] = acc;
  }
}

extern "C" void kernel_launch(void* const* d_in, const int* in_sizes, int n_in,
                              void* d_out, int out_size, void* d_ws, size_t ws_size,
                              hipStream_t stream) {
  const float* img  = (const float*)d_in[0];
  const float* cap  = (const float*)d_in[1];
  const float* adW  = (const float*)d_in[2];
  const float* adb  = (const float*)d_in[3];
  const float* qkW  = (const float*)d_in[4];
  const float* qkb  = (const float*)d_in[5];
  const float* qbW  = (const float*)d_in[6];
  const float* qbb  = (const float*)d_in[7];
  const float* qbns = (const float*)d_in[8];
  const float* qbnb = (const float*)d_in[9];
  const float* kkW  = (const float*)d_in[10];
  const float* kkb  = (const float*)d_in[11];
  const float* kbW  = (const float*)d_in[12];
  const float* kbb  = (const float*)d_in[13];
  const float* kbns = (const float*)d_in[14];
  const float* kbnb = (const float*)d_in[15];
  const float* vkW  = (const float*)d_in[16];
  const float* vkb  = (const float*)d_in[17];
  const float* vbW  = (const float*)d_in[18];
  const float* vbb  = (const float*)d_in[19];
  const float* vbns = (const float*)d_in[20];
  const float* vbnb = (const float*)d_in[21];
  const float* gamma= (const float*)d_in[22];
  const float* W1   = (const float*)d_in[23];
  const float* b1   = (const float*)d_in[24];
  const float* bn1s = (const float*)d_in[25];
  const float* bn1b = (const float*)d_in[26];
  const float* W2   = (const float*)d_in[27];
  const float* b2   = (const float*)d_in[28];
  const float* bn2s = (const float*)d_in[29];
  const float* bn2b = (const float*)d_in[30];
  const float* W3   = (const float*)d_in[31];
  const float* b3   = (const float*)d_in[32];

  float* ws    = (float*)d_ws;
  float* base  = ws + OFS_BASE;
  float* ball  = ws + OFS_BALL;
  float* mean  = ws + OFS_MEAN;
  ushort* capP = (ushort*)(ws + OFS_CAPB);
  float* rawP  = ws + OFS_RAWP;
  ushort* kall = (ushort*)(ws + OFS_RAWP);
  float* x_all = ws + OFS_X;
  float* h1    = ws + OFS_H1;    // aliases rawP/kall (dead after k_attn6)
  float* out   = (float*)d_out;

  k_mean<<<512, 256, 0, stream>>>(img, mean);
  k_base<<<128, 128, 0, stream>>>(mean, adW, adb, base);
  k_hyper<<<352, 256, 0, stream>>>(qkW, qkb, base, rawP, 22500, 0);
  k_hyper<<<352, 256, 0, stream>>>(kkW, kkb, base, rawP, 22500, 96);
  k_hyper<<<1407, 256, 0, stream>>>(vkW, vkb, base, rawP, 90000, 192);
  k_bias<<<dim3(2, 128), 256, 0, stream>>>(qbW, qbb, kbW, kbb, vbW, vbb, base, ball);
  k_capp<<<64, 256, 0, stream>>>(cap, capP);
  k_bnt3<<<dim3(32, 128), 256, 0, stream>>>(rawP, qbns, qbnb, kbns, kbnb, vbns, vbnb);
  k_attn6<<<dim3(64, 128), 256, 0, stream>>>(cap, kall, capP, ball, gamma, x_all);
  k_h1<<<dim3(4, 128), 256, 0, stream>>>(x_all, W1, b1, h1);
  k_mlp<<<128, 256, 0, stream>>>(h1, bn1s, bn1b, W2, b2, bn2s, bn2b, W3, b3, out);
}